// Round 13
// baseline (4150.414 us; speedup 1.0000x reference)
//
#include <hip/hip_runtime.h>
#include <hip/hip_bf16.h>

#define S_LEN 256
#define BATCH 64
#define EMB   300
#define EPAD  320
#define HID   512
#define G4H   2048
#define NCLS  25
#define TWOH  1024

using bf16 = __hip_bfloat16;
typedef short bf8v __attribute__((ext_vector_type(8)));   // 8 bf16 in 4 VGPRs
typedef float f32x4 __attribute__((ext_vector_type(4)));
typedef unsigned long long ull;

__device__ __forceinline__ float us2f(unsigned short u) {
    union { unsigned int i; float f; } v; v.i = ((unsigned int)u) << 16; return v.f;
}
__device__ __forceinline__ unsigned short f2us(float f) {
    union { bf16 v; unsigned short s; } cv; cv.v = __float2bfloat16(f); return cv.s;
}
__device__ __forceinline__ float sigm(float x) { return 1.f / (1.f + __expf(-x)); }

// ---------------- embedding gather: x[t][b][e] (bf16, padded to EPAD) ----------------
__global__ void embed_kernel(const int* __restrict__ ids,
                             const float* __restrict__ emb,
                             bf16* __restrict__ x)
{
    int r = blockIdx.x;            // r = t*BATCH + b
    int t = r >> 6, b = r & 63;
    int id = ids[b * S_LEN + t];
    const float* src = emb + (size_t)id * EMB;
    bf16* dst = x + (size_t)r * EPAD;
    for (int e = threadIdx.x; e < EPAD; e += blockDim.x) {
        float v = (e < EMB) ? src[e] : 0.f;
        dst[e] = __float2bfloat16(v);
    }
}

// ------- transpose recurrent weights to bf16: whTb[wl][u][g][k] = W[D+k][g*512+u] -------
__global__ void wtrans_kernel(const float* __restrict__ w_fw0, const float* __restrict__ w_bw0,
                              const float* __restrict__ w_fw1, const float* __restrict__ w_bw1,
                              bf16* __restrict__ whTb)
{
    __shared__ float tile[32][33];
    int wl = blockIdx.z;
    const float* W; int D;
    if (wl == 0)      { W = w_fw0; D = EMB; }
    else if (wl == 1) { W = w_bw0; D = EMB; }
    else if (wl == 2) { W = w_fw1; D = TWOH; }
    else              { W = w_bw1; D = TWOH; }
    int k0 = blockIdx.x * 32, n0 = blockIdx.y * 32;
    int tx = threadIdx.x, ty = threadIdx.y;
    tile[ty][tx] = W[(size_t)(D + k0 + ty) * G4H + n0 + tx];
    __syncthreads();
    int k = k0 + tx;
    int n = n0 + ty;                  // raw TF col: n = g*512 + u
    int u = n & 511, g = n >> 9;
    whTb[(((size_t)wl * 512 + u) * 4 + g) * 512 + k] = __float2bfloat16(tile[tx][ty]);
}

// --- transpose INPUT weights to bf16, gate-interleaved cols: wxTb[wl][u*4+g][k] ---
__global__ void wxtrans_kernel(const float* __restrict__ w_fw0, const float* __restrict__ w_bw0,
                               const float* __restrict__ w_fw1, const float* __restrict__ w_bw1,
                               bf16* __restrict__ wxTb)
{
    __shared__ float tile[32][33];
    int wl = blockIdx.z;
    const float* W; int D;
    if (wl == 0)      { W = w_fw0; D = EMB; }
    else if (wl == 1) { W = w_bw0; D = EMB; }
    else if (wl == 2) { W = w_fw1; D = TWOH; }
    else              { W = w_bw1; D = TWOH; }
    int k0 = blockIdx.x * 32, n0 = blockIdx.y * 32;
    int tx = threadIdx.x, ty = threadIdx.y;
    float v = (k0 + ty < D) ? W[(size_t)(k0 + ty) * G4H + n0 + tx] : 0.f;
    tile[ty][tx] = v;
    __syncthreads();
    int n = n0 + ty;                  // raw col -> interleaved row u*4+g
    int u = n & 511, g = n >> 9;
    wxTb[((size_t)wl * G4H + (u * 4 + g)) * 1024 + k0 + tx] = __float2bfloat16(tile[tx][ty]);
}

// -------- MFMA input-gate GEMM: G4[z][t][b][u*4+g] = gather(A) @ Wx + bias --------
// 128x128x64 tile, 4 waves (2x2), reg-staged LDS with 16B-chunk XOR swizzle.
// wxTb cols are gate-interleaved (u*4+g) so the epilogue stays contiguous.
__global__ __launch_bounds__(256)
void gates_mfma(const bf16* __restrict__ A, int strideA, int K,
                const bf16* __restrict__ wxTb,
                const float* __restrict__ b_fw, const float* __restrict__ b_bw,
                const int* __restrict__ lengths,
                bf16* __restrict__ G4)
{
    const int z  = blockIdx.z;
    const int m0 = blockIdx.x * 128;
    const int n0 = blockIdx.y * 128;
    const int tid = threadIdx.x;
    const float* bias = z ? b_bw : b_fw;

    __shared__ __align__(16) unsigned short smem[128 * 132];  // staging (32KB) + bounce
    unsigned short* As = smem;
    unsigned short* Bs = smem + 8192;

    const int ca = tid & 7;
    const bf16* srcA[4];
    const bf16* srcB[4];
    int lofs[4];
#pragma unroll
    for (int j = 0; j < 4; ++j) {
        int row = j * 32 + (tid >> 3);
        int r = m0 + row, t = r >> 6, b = r & 63;
        int st = t;
        if (z) { int len = lengths[b]; st = (t < len) ? (len - 1 - t) : t; }
        srcA[j] = A + (size_t)(st * 64 + b) * strideA + ca * 8;
        srcB[j] = wxTb + ((size_t)z * G4H + n0 + row) * 1024 + ca * 8;
        lofs[j] = row * 64 + ((ca ^ (row & 7)) << 3);
    }

    const int l = tid & 63, lo16 = l & 15, hi4 = l >> 4;
    const int wv = tid >> 6, wm = wv >> 1, wn = wv & 1;

    f32x4 acc[4][4];
#pragma unroll
    for (int mi = 0; mi < 4; ++mi)
#pragma unroll
        for (int ni = 0; ni < 4; ++ni)
#pragma unroll
            for (int rr = 0; rr < 4; ++rr) acc[mi][ni][rr] = 0.f;

    uint4 ra[4], rb[4];
#pragma unroll
    for (int j = 0; j < 4; ++j) {
        ra[j] = *reinterpret_cast<const uint4*>(srcA[j]);
        rb[j] = *reinterpret_cast<const uint4*>(srcB[j]);
    }

    const int nk = K >> 6;
    for (int kt = 0; kt < nk; ++kt) {
        __syncthreads();
#pragma unroll
        for (int j = 0; j < 4; ++j) {
            *reinterpret_cast<uint4*>(&As[lofs[j]]) = ra[j];
            *reinterpret_cast<uint4*>(&Bs[lofs[j]]) = rb[j];
        }
        __syncthreads();
        if (kt + 1 < nk) {
#pragma unroll
            for (int j = 0; j < 4; ++j) {
                srcA[j] += 64; srcB[j] += 64;
                ra[j] = *reinterpret_cast<const uint4*>(srcA[j]);
                rb[j] = *reinterpret_cast<const uint4*>(srcB[j]);
            }
        }
#pragma unroll
        for (int ks = 0; ks < 2; ++ks) {
            bf8v af[4], bfv[4];
#pragma unroll
            for (int mi = 0; mi < 4; ++mi) {
                int row = wm * 64 + mi * 16 + lo16;
                int c = ks * 4 + hi4;
                af[mi] = *reinterpret_cast<const bf8v*>(&As[row * 64 + ((c ^ (row & 7)) << 3)]);
            }
#pragma unroll
            for (int ni = 0; ni < 4; ++ni) {
                int row = wn * 64 + ni * 16 + lo16;
                int c = ks * 4 + hi4;
                bfv[ni] = *reinterpret_cast<const bf8v*>(&Bs[row * 64 + ((c ^ (row & 7)) << 3)]);
            }
#pragma unroll
            for (int mi = 0; mi < 4; ++mi)
#pragma unroll
                for (int ni = 0; ni < 4; ++ni)
                    acc[mi][ni] = __builtin_amdgcn_mfma_f32_16x16x32_bf16(
                        af[mi], bfv[ni], acc[mi][ni], 0, 0, 0);
        }
    }

    // ---- epilogue: LDS bounce, then contiguous [b][u*4+g] row writes ----
    __syncthreads();
    float bv[4];
#pragma unroll
    for (int ni = 0; ni < 4; ++ni) {
        int np = n0 + wn * 64 + ni * 16 + lo16;      // interleaved col
        int raw = (np & 3) * 512 + (np >> 2);        // raw TF bias index g*512+u
        bv[ni] = bias[raw];
    }
#pragma unroll
    for (int mi = 0; mi < 4; ++mi)
#pragma unroll
        for (int ni = 0; ni < 4; ++ni)
#pragma unroll
            for (int rr = 0; rr < 4; ++rr) {
                int m = wm * 64 + mi * 16 + hi4 * 4 + rr;
                int n = wn * 64 + ni * 16 + lo16;
                smem[m * 132 + n] = f2us(acc[mi][ni][rr] + bv[ni]);
            }
    __syncthreads();
    {
        int m = tid >> 1;
        int t = (m0 + m) >> 6, b = (m0 + m) & 63;
        const unsigned short* src = smem + m * 132 + (tid & 1) * 64;
        bf16* gout = G4 + (((size_t)z * S_LEN + t) * 64 + b) * G4H + n0 + (tid & 1) * 64;
#pragma unroll
        for (int j = 0; j < 16; ++j)
            *reinterpret_cast<ull*>(gout + j * 4) = *reinterpret_cast<const ull*>(src + j * 4);
    }
}

// ---------------- persistent MFMA LSTM recurrence (one layer, both dirs) ----------------
// 32 blocks = 2 dirs x 2 b-halves x 8 col-groups; 512 threads (8 waves).
// R12 structure (persistent weight A-frags, LDS-staged h, coalesced bounce stores) with
// leaner sync: double-buffered h LDS tile (kills the stage-WAR barrier), PER-WAVE flags
// (each wave drains its own stores then signals; no post-drain block barrier), and every
// wave polls the group's 64 wave-flags independently (no poll-release barrier).
// 2 syncthreads/step total.
__global__ __launch_bounds__(512, 1)
void lstm_seq(const bf16* __restrict__ G4, const bf16* __restrict__ whTb,
              const int* __restrict__ lengths, unsigned short* __restrict__ hbuf,
              unsigned int* __restrict__ flags, bf16* __restrict__ hcat)
{
    __shared__ __align__(16) unsigned short hl[2][32 * 512]; // 2x32KB h tile (swizzled)
    __shared__ __align__(16) unsigned short hout[32 * 64];   // 4KB store bounce

    const int bx = blockIdx.x;          // 0..31
    const int d  = bx >> 4;
    const int bh = (bx >> 3) & 1;
    const int cg = bx & 7;
    const int grp = d * 2 + bh;
    const int tid = threadIdx.x;        // 0..511
    const int w = tid >> 6, l = tid & 63;
    const int lo16 = l & 15, hi4 = l >> 4;
    const int u0 = cg * 64 + w * 8;

    // ---- persistent weight A-frags: row lo16 -> (u_loc=lo16>>2, g=lo16&3) ----
    bf8v afr[2][16];
#pragma unroll
    for (int mt = 0; mt < 2; ++mt) {
        const bf16* wr = whTb + (((size_t)d * 512 + u0 + mt * 4 + (lo16 >> 2)) * 4
                                 + (lo16 & 3)) * 512 + hi4 * 8;
#pragma unroll
        for (int kt = 0; kt < 16; ++kt)
            afr[mt][kt] = *reinterpret_cast<const bf8v*>(wr + kt * 32);
    }

    int len_[2];
    float c_st[2][2], h_st[2][2];
#pragma unroll
    for (int nt = 0; nt < 2; ++nt) {
        len_[nt] = lengths[bh * 32 + nt * 16 + lo16];
#pragma unroll
        for (int mt = 0; mt < 2; ++mt) { c_st[mt][nt] = 0.f; h_st[mt][nt] = 0.f; }
    }

    for (int t = 0; t < S_LEN; ++t) {
        // ---- G loads early (stable data, hides under poll) ----
        ull gv[2][2];
#pragma unroll
        for (int mt = 0; mt < 2; ++mt)
#pragma unroll
            for (int nt = 0; nt < 2; ++nt) {
                int b = bh * 32 + nt * 16 + lo16;
                int u = u0 + mt * 4 + hi4;
                gv[mt][nt] = *reinterpret_cast<const ull*>(
                    G4 + (((size_t)(d * S_LEN + t)) * 64 + b) * G4H + u * 4);
            }

        // ---- per-wave poll of the group's 64 wave-flags (step t-1) ----
        if (t > 0) {
            const unsigned int* fb = flags + ((size_t)(t - 1) * 4 + grp) * 64;
            while (!__all(__hip_atomic_load(fb + l, __ATOMIC_RELAXED,
                                            __HIP_MEMORY_SCOPE_AGENT) != 0u))
                __builtin_amdgcn_s_sleep(1);
        }

        // ---- stage h: 32b x 512u = 4096 ull, 8 coalesced loads/thread ----
        unsigned short* hlc = hl[t & 1];
        const ull* hsrc = reinterpret_cast<const ull*>(
            hbuf + ((size_t)((t & 1) * 2 + d) * 64 + bh * 32) * 512);
        ull pv[8];
#pragma unroll
        for (int i = 0; i < 8; ++i)
            pv[i] = __hip_atomic_load(hsrc + i * 512 + tid,
                                      __ATOMIC_RELAXED, __HIP_MEMORY_SCOPE_AGENT);
#pragma unroll
        for (int i = 0; i < 8; ++i) {
            int wd_ = i * 512 + tid;     // 8B word: bl = wd>>7, r = wd&127
            int bl = wd_ >> 7, r = wd_ & 127;
            int c = r >> 1, half = r & 1;
            *reinterpret_cast<ull*>(&hlc[bl * 512 + ((c ^ (bl & 7)) << 3) + (half << 2)]) = pv[i];
        }
        __syncthreads();                 // bar#2: hl visible (hout also free, see flag chain)

        // ---- acc init from G4 (reg g = gate) ----
        f32x4 acc[2][2];
#pragma unroll
        for (int mt = 0; mt < 2; ++mt)
#pragma unroll
            for (int nt = 0; nt < 2; ++nt) {
                const unsigned short* gs = reinterpret_cast<const unsigned short*>(&gv[mt][nt]);
                f32x4 av;
#pragma unroll
                for (int g = 0; g < 4; ++g) av[g] = us2f(gs[g]);
                acc[mt][nt] = av;
            }

        // ---- MFMA: 16 kt x (2 LDS B-frags + 4 mfma), weights in regs ----
#pragma unroll
        for (int kt = 0; kt < 16; ++kt) {
            bf8v bfv[2];
#pragma unroll
            for (int nt = 0; nt < 2; ++nt) {
                int bl = nt * 16 + lo16;
                int c  = kt * 4 + hi4;
                bfv[nt] = *reinterpret_cast<const bf8v*>(
                    &hlc[bl * 512 + ((c ^ (bl & 7)) << 3)]);
            }
#pragma unroll
            for (int mt = 0; mt < 2; ++mt)
#pragma unroll
                for (int nt = 0; nt < 2; ++nt)
                    acc[mt][nt] = __builtin_amdgcn_mfma_f32_16x16x32_bf16(
                        afr[mt][kt], bfv[nt], acc[mt][nt], 0, 0, 0);
        }

        // ---- pointwise: lane owns (u,b), 4 gates in regs; write h to bounce ----
#pragma unroll
        for (int mt = 0; mt < 2; ++mt)
#pragma unroll
            for (int nt = 0; nt < 2; ++nt) {
                bool msk = (t < len_[nt]);
                float i_ = sigm(acc[mt][nt][0]);
                float j_ = tanhf(acc[mt][nt][1]);
                float f_ = sigm(acc[mt][nt][2] + 1.0f);   // FORGET_BIAS
                float o_ = sigm(acc[mt][nt][3]);
                float cn = f_ * c_st[mt][nt] + i_ * j_;
                float hn = o_ * tanhf(cn);
                if (msk) c_st[mt][nt] = cn;
                h_st[mt][nt] = msk ? hn : h_st[mt][nt];
                hout[(nt * 16 + lo16) * 64 + w * 8 + mt * 4 + hi4] = f2us(h_st[mt][nt]);
            }
        __syncthreads();                 // bar#1: hout complete

        // ---- coalesced h_{t+1} stores (512 x 8B), per-wave drain + per-wave flag ----
        {
            int bl = tid >> 4, uq = (tid & 15) * 4;
            ull v = *reinterpret_cast<const ull*>(&hout[bl * 64 + uq]);
            unsigned short* hdst = hbuf + ((size_t)(((t + 1) & 1) * 2 + d) * 64
                                           + bh * 32 + bl) * 512 + cg * 64 + uq;
            __hip_atomic_store(reinterpret_cast<ull*>(hdst), v,
                               __ATOMIC_RELAXED, __HIP_MEMORY_SCOPE_AGENT);
        }
        asm volatile("s_waitcnt vmcnt(0)" ::: "memory");
        if (l == 0)
            __hip_atomic_store(&flags[((size_t)t * 4 + grp) * 64 + cg * 8 + w], 1u,
                               __ATOMIC_RELAXED, __HIP_MEMORY_SCOPE_AGENT);

        // ---- shadow: hcat stores ----
#pragma unroll
        for (int mt = 0; mt < 2; ++mt)
#pragma unroll
            for (int nt = 0; nt < 2; ++nt) {
                int b = bh * 32 + nt * 16 + lo16;
                int u = u0 + mt * 4 + hi4;
                bool msk = (t < len_[nt]);
                int p = (d == 1 && msk) ? (len_[nt] - 1 - t) : t;
                hcat[((size_t)p * 64 + b) * TWOH + (size_t)d * 512 + u] =
                    __float2bfloat16(msk ? h_st[mt][nt] : 0.f);
            }
    }
}

// ---------------- dense + softmax: out[b][s][c] ----------------
__global__ __launch_bounds__(256)
void dense_softmax(const bf16* __restrict__ h, const float* __restrict__ wd,
                   const float* __restrict__ bd, float* __restrict__ out)
{
    __shared__ __align__(16) bf16 wdT[NCLS][1032];
    for (int i = threadIdx.x; i < TWOH * NCLS; i += 256) {
        int k = i / NCLS, c = i % NCLS;    // wd[k][c]
        wdT[c][k] = __float2bfloat16(wd[i]);
    }
    __syncthreads();
    const int c  = threadIdx.x & 31;
    const int rl = threadIdx.x >> 5;
#pragma unroll 1
    for (int pass = 0; pass < 8; ++pass) {
        int r = blockIdx.x * 64 + pass * 8 + rl;   // r = s*BATCH + b
        const bf16* hrow = h + (size_t)r * TWOH;
        float acc = -1e30f;
        if (c < NCLS) {
            acc = 0.f;
            for (int k = 0; k < TWOH; k += 8) {
                uint4 hv = *reinterpret_cast<const uint4*>(hrow + k);
                uint4 wv = *reinterpret_cast<const uint4*>(&wdT[c][k]);
                const unsigned short* hs  = reinterpret_cast<const unsigned short*>(&hv);
                const unsigned short* wsp = reinterpret_cast<const unsigned short*>(&wv);
#pragma unroll
                for (int j = 0; j < 8; ++j) acc += us2f(hs[j]) * us2f(wsp[j]);
            }
            acc += bd[c];
        }
        float mx = acc;
#pragma unroll
        for (int o = 16; o; o >>= 1) mx = fmaxf(mx, __shfl_xor(mx, o, 32));
        float e = (c < NCLS) ? __expf(acc - mx) : 0.f;
        float sm = e;
#pragma unroll
        for (int o = 16; o; o >>= 1) sm += __shfl_xor(sm, o, 32);
        if (c < NCLS) {
            int s = r >> 6, b = r & 63;
            out[((size_t)b * S_LEN + s) * NCLS + c] = e / sm;
        }
    }
}

extern "C" void kernel_launch(void* const* d_in, const int* in_sizes, int n_in,
                              void* d_out, int out_size, void* d_ws, size_t ws_size,
                              hipStream_t stream)
{
    const int*   ids   = (const int*)  d_in[0];
    const int*   lens  = (const int*)  d_in[1];
    const float* emb   = (const float*)d_in[2];
    const float* w_fw0 = (const float*)d_in[3];
    const float* b_fw0 = (const float*)d_in[4];
    const float* w_bw0 = (const float*)d_in[5];
    const float* b_bw0 = (const float*)d_in[6];
    const float* w_fw1 = (const float*)d_in[7];
    const float* b_fw1 = (const float*)d_in[8];
    const float* w_bw1 = (const float*)d_in[9];
    const float* b_bw1 = (const float*)d_in[10];
    const float* wd    = (const float*)d_in[11];
    const float* bd    = (const float*)d_in[12];
    float* out = (float*)d_out;

    char* ws = (char*)d_ws;
    size_t off = 0;
    auto alloc = [&](size_t bytes) {
        void* p = ws + off;
        off += (bytes + 255) & ~(size_t)255;
        return p;
    };
    bf16*  x      = (bf16*) alloc((size_t)S_LEN * BATCH * EPAD * 2);
    bf16*  G4     = (bf16*) alloc((size_t)2 * S_LEN * BATCH * G4H * 2);
    bf16*  hcat0  = (bf16*) alloc((size_t)S_LEN * BATCH * TWOH * 2);
    bf16*  hcat1  = (bf16*) alloc((size_t)S_LEN * BATCH * TWOH * 2);
    bf16*  whTb   = (bf16*) alloc((size_t)4 * 512 * 4 * 512 * 2);
    bf16*  wxTb   = (bf16*) alloc((size_t)4 * G4H * 1024 * 2);
    unsigned short* hbuf = (unsigned short*)alloc((size_t)2 * 2 * BATCH * HID * 2);
    unsigned int* flags  = (unsigned int*) alloc((size_t)S_LEN * 4 * 64 * 4);

    embed_kernel<<<S_LEN * BATCH, 128, 0, stream>>>(ids, emb, x);
    wtrans_kernel<<<dim3(16, 64, 4), dim3(32, 32), 0, stream>>>(w_fw0, w_bw0, w_fw1, w_bw1, whTb);
    wxtrans_kernel<<<dim3(32, 64, 4), dim3(32, 32), 0, stream>>>(w_fw0, w_bw0, w_fw1, w_bw1, wxTb);

    for (int layer = 0; layer < 2; ++layer) {
        hipMemsetAsync(hbuf, 0, (size_t)2 * 2 * BATCH * HID * 2, stream);
        hipMemsetAsync(flags, 0, (size_t)S_LEN * 4 * 64 * 4, stream);
        const bf16* Ain   = layer ? hcat0 : x;
        int strideA       = layer ? TWOH : EPAD;
        int K             = layer ? 1024 : EPAD;
        const float* bfp  = layer ? b_fw1 : b_fw0;
        const float* bbp  = layer ? b_bw1 : b_bw0;
        bf16* hcat        = layer ? hcat1 : hcat0;

        gates_mfma<<<dim3(128, 16, 2), 256, 0, stream>>>(
            Ain, strideA, K, wxTb + (size_t)layer * 2 * G4H * 1024,
            bfp, bbp, lens, G4);

        const bf16*  Gp   = G4;
        const bf16*  whp  = whTb + (size_t)layer * 2 * 512 * 4 * 512;
        const int*   lnp  = lens;
        unsigned short* hbp = hbuf;
        unsigned int* flp = flags;
        bf16*        hcp  = hcat;
        void* args[6] = { &Gp, &whp, &lnp, &hbp, &flp, &hcp };
        hipLaunchCooperativeKernel(lstm_seq, dim3(32), dim3(512), args, 0, stream);
    }
    dense_softmax<<<256, 256, 0, stream>>>(hcat1, wd, bd, out);

    (void)in_sizes; (void)n_in; (void)out_size; (void)ws_size;
}

// Round 14
// 3586.899 us; speedup vs baseline: 1.1571x; 1.1571x over previous
//
#include <hip/hip_runtime.h>
#include <hip/hip_bf16.h>

#define S_LEN 256
#define BATCH 64
#define EMB   300
#define EPAD  320
#define HID   512
#define G4H   2048
#define NCLS  25
#define TWOH  1024

using bf16 = __hip_bfloat16;
typedef short bf8v __attribute__((ext_vector_type(8)));   // 8 bf16 in 4 VGPRs
typedef float f32x4 __attribute__((ext_vector_type(4)));
typedef unsigned long long ull;

__device__ __forceinline__ float us2f(unsigned short u) {
    union { unsigned int i; float f; } v; v.i = ((unsigned int)u) << 16; return v.f;
}
__device__ __forceinline__ unsigned short f2us(float f) {
    union { bf16 v; unsigned short s; } cv; cv.v = __float2bfloat16(f); return cv.s;
}
__device__ __forceinline__ float sigm(float x) { return 1.f / (1.f + __expf(-x)); }

// ---------------- embedding gather: x[t][b][e] (bf16, padded to EPAD) ----------------
__global__ void embed_kernel(const int* __restrict__ ids,
                             const float* __restrict__ emb,
                             bf16* __restrict__ x)
{
    int r = blockIdx.x;            // r = t*BATCH + b
    int t = r >> 6, b = r & 63;
    int id = ids[b * S_LEN + t];
    const float* src = emb + (size_t)id * EMB;
    bf16* dst = x + (size_t)r * EPAD;
    for (int e = threadIdx.x; e < EPAD; e += blockDim.x) {
        float v = (e < EMB) ? src[e] : 0.f;
        dst[e] = __float2bfloat16(v);
    }
}

// ------- transpose recurrent weights to bf16: whTb[wl][u][g][k] = W[D+k][g*512+u] -------
__global__ void wtrans_kernel(const float* __restrict__ w_fw0, const float* __restrict__ w_bw0,
                              const float* __restrict__ w_fw1, const float* __restrict__ w_bw1,
                              bf16* __restrict__ whTb)
{
    __shared__ float tile[32][33];
    int wl = blockIdx.z;
    const float* W; int D;
    if (wl == 0)      { W = w_fw0; D = EMB; }
    else if (wl == 1) { W = w_bw0; D = EMB; }
    else if (wl == 2) { W = w_fw1; D = TWOH; }
    else              { W = w_bw1; D = TWOH; }
    int k0 = blockIdx.x * 32, n0 = blockIdx.y * 32;
    int tx = threadIdx.x, ty = threadIdx.y;
    tile[ty][tx] = W[(size_t)(D + k0 + ty) * G4H + n0 + tx];
    __syncthreads();
    int k = k0 + tx;
    int n = n0 + ty;                  // raw TF col: n = g*512 + u
    int u = n & 511, g = n >> 9;
    whTb[(((size_t)wl * 512 + u) * 4 + g) * 512 + k] = __float2bfloat16(tile[tx][ty]);
}

// --- transpose INPUT weights to bf16, gate-interleaved cols: wxTb[wl][u*4+g][k] ---
__global__ void wxtrans_kernel(const float* __restrict__ w_fw0, const float* __restrict__ w_bw0,
                               const float* __restrict__ w_fw1, const float* __restrict__ w_bw1,
                               bf16* __restrict__ wxTb)
{
    __shared__ float tile[32][33];
    int wl = blockIdx.z;
    const float* W; int D;
    if (wl == 0)      { W = w_fw0; D = EMB; }
    else if (wl == 1) { W = w_bw0; D = EMB; }
    else if (wl == 2) { W = w_fw1; D = TWOH; }
    else              { W = w_bw1; D = TWOH; }
    int k0 = blockIdx.x * 32, n0 = blockIdx.y * 32;
    int tx = threadIdx.x, ty = threadIdx.y;
    float v = (k0 + ty < D) ? W[(size_t)(k0 + ty) * G4H + n0 + tx] : 0.f;
    tile[ty][tx] = v;
    __syncthreads();
    int n = n0 + ty;                  // raw col -> interleaved row u*4+g
    int u = n & 511, g = n >> 9;
    wxTb[((size_t)wl * G4H + (u * 4 + g)) * 1024 + k0 + tx] = __float2bfloat16(tile[tx][ty]);
}

// -------- MFMA input-gate GEMM: G4[z][t][b][u*4+g] = gather(A) @ Wx + bias --------
// 256x128x64 tile, 8 waves (4x2), 512 threads, reg-staged LDS with 16B-chunk XOR swizzle.
// 2x work per barrier pair vs the 128x128 version. Epilogue bounce in two 128-row passes.
__global__ __launch_bounds__(512)
void gates_mfma(const bf16* __restrict__ A, int strideA, int K,
                const bf16* __restrict__ wxTb,
                const float* __restrict__ b_fw, const float* __restrict__ b_bw,
                const int* __restrict__ lengths,
                bf16* __restrict__ G4)
{
    const int z  = blockIdx.z;
    const int m0 = blockIdx.x * 256;
    const int n0 = blockIdx.y * 128;
    const int tid = threadIdx.x;        // 0..511
    const float* bias = z ? b_bw : b_fw;

    __shared__ __align__(16) unsigned short smem[24576];  // As 256x64 | Bs 128x64 (48KB)
    unsigned short* As = smem;
    unsigned short* Bs = smem + 16384;

    const int ca = tid & 7;
    const bf16* srcA[4];
    const bf16* srcB[2];
    int lofsA[4], lofsB[2];
#pragma unroll
    for (int j = 0; j < 4; ++j) {
        int row = j * 64 + (tid >> 3);
        int r = m0 + row, t = r >> 6, b = r & 63;
        int st = t;
        if (z) { int len = lengths[b]; st = (t < len) ? (len - 1 - t) : t; }
        srcA[j] = A + (size_t)(st * 64 + b) * strideA + ca * 8;
        lofsA[j] = row * 64 + ((ca ^ (row & 7)) << 3);
    }
#pragma unroll
    for (int j = 0; j < 2; ++j) {
        int row = j * 64 + (tid >> 3);
        srcB[j] = wxTb + ((size_t)z * G4H + n0 + row) * 1024 + ca * 8;
        lofsB[j] = row * 64 + ((ca ^ (row & 7)) << 3);
    }

    const int l = tid & 63, lo16 = l & 15, hi4 = l >> 4;
    const int wv = tid >> 6, wm = wv >> 1, wn = wv & 1;   // wm 0..3, wn 0..1

    f32x4 acc[4][4];
#pragma unroll
    for (int mi = 0; mi < 4; ++mi)
#pragma unroll
        for (int ni = 0; ni < 4; ++ni)
#pragma unroll
            for (int rr = 0; rr < 4; ++rr) acc[mi][ni][rr] = 0.f;

    uint4 ra[4], rb[2];
#pragma unroll
    for (int j = 0; j < 4; ++j) ra[j] = *reinterpret_cast<const uint4*>(srcA[j]);
#pragma unroll
    for (int j = 0; j < 2; ++j) rb[j] = *reinterpret_cast<const uint4*>(srcB[j]);

    const int nk = K >> 6;
    for (int kt = 0; kt < nk; ++kt) {
        __syncthreads();
#pragma unroll
        for (int j = 0; j < 4; ++j) *reinterpret_cast<uint4*>(&As[lofsA[j]]) = ra[j];
#pragma unroll
        for (int j = 0; j < 2; ++j) *reinterpret_cast<uint4*>(&Bs[lofsB[j]]) = rb[j];
        __syncthreads();
        if (kt + 1 < nk) {
#pragma unroll
            for (int j = 0; j < 4; ++j) {
                srcA[j] += 64;
                ra[j] = *reinterpret_cast<const uint4*>(srcA[j]);
            }
#pragma unroll
            for (int j = 0; j < 2; ++j) {
                srcB[j] += 64;
                rb[j] = *reinterpret_cast<const uint4*>(srcB[j]);
            }
        }
#pragma unroll
        for (int ks = 0; ks < 2; ++ks) {
            bf8v af[4], bfv[4];
#pragma unroll
            for (int mi = 0; mi < 4; ++mi) {
                int row = wm * 64 + mi * 16 + lo16;
                int c = ks * 4 + hi4;
                af[mi] = *reinterpret_cast<const bf8v*>(&As[row * 64 + ((c ^ (row & 7)) << 3)]);
            }
#pragma unroll
            for (int ni = 0; ni < 4; ++ni) {
                int row = wn * 64 + ni * 16 + lo16;
                int c = ks * 4 + hi4;
                bfv[ni] = *reinterpret_cast<const bf8v*>(&Bs[row * 64 + ((c ^ (row & 7)) << 3)]);
            }
#pragma unroll
            for (int mi = 0; mi < 4; ++mi)
#pragma unroll
                for (int ni = 0; ni < 4; ++ni)
                    acc[mi][ni] = __builtin_amdgcn_mfma_f32_16x16x32_bf16(
                        af[mi], bfv[ni], acc[mi][ni], 0, 0, 0);
        }
    }

    // ---- epilogue: two 128-row bounce passes, contiguous [b][u*4+g] writes ----
    float bv[4];
#pragma unroll
    for (int ni = 0; ni < 4; ++ni) {
        int np = n0 + wn * 64 + ni * 16 + lo16;      // interleaved col
        int raw = (np & 3) * 512 + (np >> 2);        // raw TF bias index g*512+u
        bv[ni] = bias[raw];
    }
#pragma unroll
    for (int h = 0; h < 2; ++h) {
        __syncthreads();
        if ((wm >> 1) == h) {
#pragma unroll
            for (int mi = 0; mi < 4; ++mi)
#pragma unroll
                for (int ni = 0; ni < 4; ++ni)
#pragma unroll
                    for (int rr = 0; rr < 4; ++rr) {
                        int m = (wm & 1) * 64 + mi * 16 + hi4 * 4 + rr;   // 0..127
                        int n = wn * 64 + ni * 16 + lo16;
                        smem[m * 132 + n] = f2us(acc[mi][ni][rr] + bv[ni]);
                    }
        }
        __syncthreads();
        {
            int row = tid >> 2;
            int cs  = (tid & 3) * 32;
            int m = m0 + h * 128 + row;
            int tt = m >> 6, b = m & 63;
            const unsigned short* src = smem + row * 132 + cs;
            bf16* gout = G4 + (((size_t)z * S_LEN + tt) * 64 + b) * G4H + n0 + cs;
#pragma unroll
            for (int j = 0; j < 8; ++j)
                *reinterpret_cast<ull*>(gout + j * 4) =
                    *reinterpret_cast<const ull*>(src + j * 4);
        }
    }
}

// ---------------- persistent MFMA LSTM recurrence (one layer, both dirs) ----------------
// R12 VERBATIM (best measured: 1.36 ms/layer). 32 blocks = 2 dirs x 2 b-halves x 8
// col-groups; 512 threads (8 waves). Persistent weight A-frags (AGPR-parked), LDS-staged
// h, coalesced bounce stores, per-BLOCK flags (8/group) polled by tid<16... tid<8 lanes.
__global__ __launch_bounds__(512, 1)
void lstm_seq(const bf16* __restrict__ G4, const bf16* __restrict__ whTb,
              const int* __restrict__ lengths, unsigned short* __restrict__ hbuf,
              unsigned int* __restrict__ flags, bf16* __restrict__ hcat)
{
    __shared__ __align__(16) unsigned short hl[32 * 512];    // 32KB h tile (swizzled)
    __shared__ __align__(16) unsigned short hout[32 * 64];   // 4KB store bounce

    const int bx = blockIdx.x;          // 0..31
    const int d  = bx >> 4;
    const int bh = (bx >> 3) & 1;
    const int cg = bx & 7;
    const int tid = threadIdx.x;        // 0..511
    const int w = tid >> 6, l = tid & 63;
    const int lo16 = l & 15, hi4 = l >> 4;
    const int u0 = cg * 64 + w * 8;

    // ---- persistent weight A-frags: row lo16 -> (u_loc=lo16>>2, g=lo16&3) ----
    bf8v afr[2][16];
#pragma unroll
    for (int mt = 0; mt < 2; ++mt) {
        const bf16* wr = whTb + (((size_t)d * 512 + u0 + mt * 4 + (lo16 >> 2)) * 4
                                 + (lo16 & 3)) * 512 + hi4 * 8;
#pragma unroll
        for (int kt = 0; kt < 16; ++kt)
            afr[mt][kt] = *reinterpret_cast<const bf8v*>(wr + kt * 32);
    }

    int len_[2];
    float c_st[2][2], h_st[2][2];
#pragma unroll
    for (int nt = 0; nt < 2; ++nt) {
        len_[nt] = lengths[bh * 32 + nt * 16 + lo16];
#pragma unroll
        for (int mt = 0; mt < 2; ++mt) { c_st[mt][nt] = 0.f; h_st[mt][nt] = 0.f; }
    }

    for (int t = 0; t < S_LEN; ++t) {
        // ---- G loads early (stable data, hides under poll) ----
        ull gv[2][2];
#pragma unroll
        for (int mt = 0; mt < 2; ++mt)
#pragma unroll
            for (int nt = 0; nt < 2; ++nt) {
                int b = bh * 32 + nt * 16 + lo16;
                int u = u0 + mt * 4 + hi4;
                gv[mt][nt] = *reinterpret_cast<const ull*>(
                    G4 + (((size_t)(d * S_LEN + t)) * 64 + b) * G4H + u * 4);
            }

        // ---- wait for the 8 producer blocks of (d,bh) to finish step t-1 ----
        if (t > 0 && tid < 8) {
            const unsigned int* fb = flags + (size_t)(t - 1) * 32 + (d * 2 + bh) * 8;
            while (__hip_atomic_load(fb + tid, __ATOMIC_RELAXED,
                                     __HIP_MEMORY_SCOPE_AGENT) == 0u)
                __builtin_amdgcn_s_sleep(2);
        }
        __syncthreads();        // poll done + prior step's MFMA reads of hl done

        // ---- stage h: 32b x 512u = 4096 ull, 8 coalesced loads/thread ----
        const ull* hsrc = reinterpret_cast<const ull*>(
            hbuf + ((size_t)((t & 1) * 2 + d) * 64 + bh * 32) * 512);
        ull pv[8];
#pragma unroll
        for (int i = 0; i < 8; ++i)
            pv[i] = __hip_atomic_load(hsrc + i * 512 + tid,
                                      __ATOMIC_RELAXED, __HIP_MEMORY_SCOPE_AGENT);
#pragma unroll
        for (int i = 0; i < 8; ++i) {
            int wd_ = i * 512 + tid;     // 8B word: bl = wd>>7, r = wd&127
            int bl = wd_ >> 7, r = wd_ & 127;
            int c = r >> 1, half = r & 1;
            *reinterpret_cast<ull*>(&hl[bl * 512 + ((c ^ (bl & 7)) << 3) + (half << 2)]) = pv[i];
        }
        __syncthreads();

        // ---- acc init from G4 (reg g = gate) ----
        f32x4 acc[2][2];
#pragma unroll
        for (int mt = 0; mt < 2; ++mt)
#pragma unroll
            for (int nt = 0; nt < 2; ++nt) {
                const unsigned short* gs = reinterpret_cast<const unsigned short*>(&gv[mt][nt]);
                f32x4 av;
#pragma unroll
                for (int g = 0; g < 4; ++g) av[g] = us2f(gs[g]);
                acc[mt][nt] = av;
            }

        // ---- MFMA: 16 kt x (2 LDS B-frags + 4 mfma), weights in regs ----
#pragma unroll
        for (int kt = 0; kt < 16; ++kt) {
            bf8v bfv[2];
#pragma unroll
            for (int nt = 0; nt < 2; ++nt) {
                int bl = nt * 16 + lo16;
                int c  = kt * 4 + hi4;
                bfv[nt] = *reinterpret_cast<const bf8v*>(
                    &hl[bl * 512 + ((c ^ (bl & 7)) << 3)]);
            }
#pragma unroll
            for (int mt = 0; mt < 2; ++mt)
#pragma unroll
                for (int nt = 0; nt < 2; ++nt)
                    acc[mt][nt] = __builtin_amdgcn_mfma_f32_16x16x32_bf16(
                        afr[mt][kt], bfv[nt], acc[mt][nt], 0, 0, 0);
        }

        // ---- pointwise: lane owns (u,b), 4 gates in regs; write h to bounce ----
#pragma unroll
        for (int mt = 0; mt < 2; ++mt)
#pragma unroll
            for (int nt = 0; nt < 2; ++nt) {
                bool msk = (t < len_[nt]);
                float i_ = sigm(acc[mt][nt][0]);
                float j_ = tanhf(acc[mt][nt][1]);
                float f_ = sigm(acc[mt][nt][2] + 1.0f);   // FORGET_BIAS
                float o_ = sigm(acc[mt][nt][3]);
                float cn = f_ * c_st[mt][nt] + i_ * j_;
                float hn = o_ * tanhf(cn);
                if (msk) c_st[mt][nt] = cn;
                h_st[mt][nt] = msk ? hn : h_st[mt][nt];
                hout[(nt * 16 + lo16) * 64 + w * 8 + mt * 4 + hi4] = f2us(h_st[mt][nt]);
            }
        __syncthreads();

        // ---- coalesced h_{t+1} stores: 512 x 8B ----
        {
            int bl = tid >> 4, uq = (tid & 15) * 4;
            ull v = *reinterpret_cast<const ull*>(&hout[bl * 64 + uq]);
            unsigned short* hdst = hbuf + ((size_t)(((t + 1) & 1) * 2 + d) * 64
                                           + bh * 32 + bl) * 512 + cg * 64 + uq;
            __hip_atomic_store(reinterpret_cast<ull*>(hdst), v,
                               __ATOMIC_RELAXED, __HIP_MEMORY_SCOPE_AGENT);
        }
        asm volatile("s_waitcnt vmcnt(0)" ::: "memory");
        __syncthreads();
        if (tid == 0)
            __hip_atomic_store(&flags[(size_t)t * 32 + (d * 2 + bh) * 8 + cg], 1u,
                               __ATOMIC_RELAXED, __HIP_MEMORY_SCOPE_AGENT);

        // ---- shadow: hcat stores ----
#pragma unroll
        for (int mt = 0; mt < 2; ++mt)
#pragma unroll
            for (int nt = 0; nt < 2; ++nt) {
                int b = bh * 32 + nt * 16 + lo16;
                int u = u0 + mt * 4 + hi4;
                bool msk = (t < len_[nt]);
                int p = (d == 1 && msk) ? (len_[nt] - 1 - t) : t;
                hcat[((size_t)p * 64 + b) * TWOH + (size_t)d * 512 + u] =
                    __float2bfloat16(msk ? h_st[mt][nt] : 0.f);
            }
    }
}

// ---------------- dense + softmax: out[b][s][c] ----------------
__global__ __launch_bounds__(256)
void dense_softmax(const bf16* __restrict__ h, const float* __restrict__ wd,
                   const float* __restrict__ bd, float* __restrict__ out)
{
    __shared__ __align__(16) bf16 wdT[NCLS][1032];
    for (int i = threadIdx.x; i < TWOH * NCLS; i += 256) {
        int k = i / NCLS, c = i % NCLS;    // wd[k][c]
        wdT[c][k] = __float2bfloat16(wd[i]);
    }
    __syncthreads();
    const int c  = threadIdx.x & 31;
    const int rl = threadIdx.x >> 5;
#pragma unroll 1
    for (int pass = 0; pass < 8; ++pass) {
        int r = blockIdx.x * 64 + pass * 8 + rl;   // r = s*BATCH + b
        const bf16* hrow = h + (size_t)r * TWOH;
        float acc = -1e30f;
        if (c < NCLS) {
            acc = 0.f;
            for (int k = 0; k < TWOH; k += 8) {
                uint4 hv = *reinterpret_cast<const uint4*>(hrow + k);
                uint4 wv = *reinterpret_cast<const uint4*>(&wdT[c][k]);
                const unsigned short* hs  = reinterpret_cast<const unsigned short*>(&hv);
                const unsigned short* wsp = reinterpret_cast<const unsigned short*>(&wv);
#pragma unroll
                for (int j = 0; j < 8; ++j) acc += us2f(hs[j]) * us2f(wsp[j]);
            }
            acc += bd[c];
        }
        float mx = acc;
#pragma unroll
        for (int o = 16; o; o >>= 1) mx = fmaxf(mx, __shfl_xor(mx, o, 32));
        float e = (c < NCLS) ? __expf(acc - mx) : 0.f;
        float sm = e;
#pragma unroll
        for (int o = 16; o; o >>= 1) sm += __shfl_xor(sm, o, 32);
        if (c < NCLS) {
            int s = r >> 6, b = r & 63;
            out[((size_t)b * S_LEN + s) * NCLS + c] = e / sm;
        }
    }
}

extern "C" void kernel_launch(void* const* d_in, const int* in_sizes, int n_in,
                              void* d_out, int out_size, void* d_ws, size_t ws_size,
                              hipStream_t stream)
{
    const int*   ids   = (const int*)  d_in[0];
    const int*   lens  = (const int*)  d_in[1];
    const float* emb   = (const float*)d_in[2];
    const float* w_fw0 = (const float*)d_in[3];
    const float* b_fw0 = (const float*)d_in[4];
    const float* w_bw0 = (const float*)d_in[5];
    const float* b_bw0 = (const float*)d_in[6];
    const float* w_fw1 = (const float*)d_in[7];
    const float* b_fw1 = (const float*)d_in[8];
    const float* w_bw1 = (const float*)d_in[9];
    const float* b_bw1 = (const float*)d_in[10];
    const float* wd    = (const float*)d_in[11];
    const float* bd    = (const float*)d_in[12];
    float* out = (float*)d_out;

    char* ws = (char*)d_ws;
    size_t off = 0;
    auto alloc = [&](size_t bytes) {
        void* p = ws + off;
        off += (bytes + 255) & ~(size_t)255;
        return p;
    };
    bf16*  x      = (bf16*) alloc((size_t)S_LEN * BATCH * EPAD * 2);
    bf16*  G4     = (bf16*) alloc((size_t)2 * S_LEN * BATCH * G4H * 2);
    bf16*  hcat0  = (bf16*) alloc((size_t)S_LEN * BATCH * TWOH * 2);
    bf16*  hcat1  = (bf16*) alloc((size_t)S_LEN * BATCH * TWOH * 2);
    bf16*  whTb   = (bf16*) alloc((size_t)4 * 512 * 4 * 512 * 2);
    bf16*  wxTb   = (bf16*) alloc((size_t)4 * G4H * 1024 * 2);
    unsigned short* hbuf = (unsigned short*)alloc((size_t)2 * 2 * BATCH * HID * 2);
    unsigned int* flags  = (unsigned int*) alloc((size_t)2 * S_LEN * 32 * 4);

    embed_kernel<<<S_LEN * BATCH, 128, 0, stream>>>(ids, emb, x);
    wtrans_kernel<<<dim3(16, 64, 4), dim3(32, 32), 0, stream>>>(w_fw0, w_bw0, w_fw1, w_bw1, whTb);
    wxtrans_kernel<<<dim3(32, 64, 4), dim3(32, 32), 0, stream>>>(w_fw0, w_bw0, w_fw1, w_bw1, wxTb);
    hipMemsetAsync(flags, 0, (size_t)2 * S_LEN * 32 * 4, stream);

    for (int layer = 0; layer < 2; ++layer) {
        hipMemsetAsync(hbuf, 0, (size_t)2 * 2 * BATCH * HID * 2, stream);
        const bf16* Ain   = layer ? hcat0 : x;
        int strideA       = layer ? TWOH : EPAD;
        int K             = layer ? 1024 : EPAD;
        const float* bfp  = layer ? b_fw1 : b_fw0;
        const float* bbp  = layer ? b_bw1 : b_bw0;
        bf16* hcat        = layer ? hcat1 : hcat0;

        gates_mfma<<<dim3(64, 16, 2), 512, 0, stream>>>(
            Ain, strideA, K, wxTb + (size_t)layer * 2 * G4H * 1024,
            bfp, bbp, lens, G4);

        const bf16*  Gp   = G4;
        const bf16*  whp  = whTb + (size_t)layer * 2 * 512 * 4 * 512;
        const int*   lnp  = lens;
        unsigned short* hbp = hbuf;
        unsigned int* flp = flags + (size_t)layer * S_LEN * 32;
        bf16*        hcp  = hcat;
        void* args[6] = { &Gp, &whp, &lnp, &hbp, &flp, &hcp };
        hipLaunchCooperativeKernel(lstm_seq, dim3(32), dim3(512), args, 0, stream);
    }
    dense_softmax<<<256, 256, 0, stream>>>(hcat1, wd, bd, out);

    (void)in_sizes; (void)n_in; (void)out_size; (void)ws_size;
}

// Round 16
// 3573.517 us; speedup vs baseline: 1.1614x; 1.0037x over previous
//
#include <hip/hip_runtime.h>
#include <hip/hip_bf16.h>

#define S_LEN 256
#define BATCH 64
#define EMB   300
#define EPAD  320
#define HID   512
#define G4H   2048
#define NCLS  25
#define TWOH  1024

using bf16 = __hip_bfloat16;
typedef short bf8v __attribute__((ext_vector_type(8)));   // 8 bf16 in 4 VGPRs
typedef float f32x4 __attribute__((ext_vector_type(4)));
typedef unsigned long long ull;

__device__ __forceinline__ float us2f(unsigned short u) {
    union { unsigned int i; float f; } v; v.i = ((unsigned int)u) << 16; return v.f;
}
__device__ __forceinline__ unsigned short f2us(float f) {
    union { bf16 v; unsigned short s; } cv; cv.v = __float2bfloat16(f); return cv.s;
}
__device__ __forceinline__ float sigm(float x) { return 1.f / (1.f + __expf(-x)); }

// ---------------- embedding gather: x[t][b][e] (bf16, padded to EPAD) ----------------
__global__ void embed_kernel(const int* __restrict__ ids,
                             const float* __restrict__ emb,
                             bf16* __restrict__ x)
{
    int r = blockIdx.x;            // r = t*BATCH + b
    int t = r >> 6, b = r & 63;
    int id = ids[b * S_LEN + t];
    const float* src = emb + (size_t)id * EMB;
    bf16* dst = x + (size_t)r * EPAD;
    for (int e = threadIdx.x; e < EPAD; e += blockDim.x) {
        float v = (e < EMB) ? src[e] : 0.f;
        dst[e] = __float2bfloat16(v);
    }
}

// ------- transpose recurrent weights to bf16: whTb[wl][u][g][k] = W[D+k][g*512+u] -------
__global__ void wtrans_kernel(const float* __restrict__ w_fw0, const float* __restrict__ w_bw0,
                              const float* __restrict__ w_fw1, const float* __restrict__ w_bw1,
                              bf16* __restrict__ whTb)
{
    __shared__ float tile[32][33];
    int wl = blockIdx.z;
    const float* W; int D;
    if (wl == 0)      { W = w_fw0; D = EMB; }
    else if (wl == 1) { W = w_bw0; D = EMB; }
    else if (wl == 2) { W = w_fw1; D = TWOH; }
    else              { W = w_bw1; D = TWOH; }
    int k0 = blockIdx.x * 32, n0 = blockIdx.y * 32;
    int tx = threadIdx.x, ty = threadIdx.y;
    tile[ty][tx] = W[(size_t)(D + k0 + ty) * G4H + n0 + tx];
    __syncthreads();
    int k = k0 + tx;
    int n = n0 + ty;                  // raw TF col: n = g*512 + u
    int u = n & 511, g = n >> 9;
    whTb[(((size_t)wl * 512 + u) * 4 + g) * 512 + k] = __float2bfloat16(tile[tx][ty]);
}

// --- per-layer transpose of INPUT weights, gate-interleaved cols: wxTb[z][u*4+g][k] ---
__global__ void wxtrans_kernel(const float* __restrict__ w_fw, const float* __restrict__ w_bw,
                               int D, bf16* __restrict__ wxTb)
{
    __shared__ float tile[32][33];
    int z = blockIdx.z;
    const float* W = z ? w_bw : w_fw;
    int k0 = blockIdx.x * 32, n0 = blockIdx.y * 32;
    int tx = threadIdx.x, ty = threadIdx.y;
    float v = (k0 + ty < D) ? W[(size_t)(k0 + ty) * G4H + n0 + tx] : 0.f;
    tile[ty][tx] = v;
    __syncthreads();
    int n = n0 + ty;                  // raw col -> interleaved row u*4+g
    int u = n & 511, g = n >> 9;
    wxTb[((size_t)z * G4H + (u * 4 + g)) * 1024 + k0 + tx] = __float2bfloat16(tile[tx][ty]);
}

// -------- MFMA input-gate GEMM: G4[z][t][b][u*4+g] = gather(A) @ Wx + bias --------
// 256x128x64 tile, 8 waves (4x2), 512 threads, reg-staged LDS with 16B-chunk XOR swizzle.
__global__ __launch_bounds__(512)
void gates_mfma(const bf16* __restrict__ A, int strideA, int K,
                const bf16* __restrict__ wxTb,
                const float* __restrict__ b_fw, const float* __restrict__ b_bw,
                const int* __restrict__ lengths,
                bf16* __restrict__ G4)
{
    const int z  = blockIdx.z;
    const int m0 = blockIdx.x * 256;
    const int n0 = blockIdx.y * 128;
    const int tid = threadIdx.x;        // 0..511
    const float* bias = z ? b_bw : b_fw;

    __shared__ __align__(16) unsigned short smem[24576];  // As 256x64 | Bs 128x64 (48KB)
    unsigned short* As = smem;
    unsigned short* Bs = smem + 16384;

    const int ca = tid & 7;
    const bf16* srcA[4];
    const bf16* srcB[2];
    int lofsA[4], lofsB[2];
#pragma unroll
    for (int j = 0; j < 4; ++j) {
        int row = j * 64 + (tid >> 3);
        int r = m0 + row, t = r >> 6, b = r & 63;
        int st = t;
        if (z) { int len = lengths[b]; st = (t < len) ? (len - 1 - t) : t; }
        srcA[j] = A + (size_t)(st * 64 + b) * strideA + ca * 8;
        lofsA[j] = row * 64 + ((ca ^ (row & 7)) << 3);
    }
#pragma unroll
    for (int j = 0; j < 2; ++j) {
        int row = j * 64 + (tid >> 3);
        srcB[j] = wxTb + ((size_t)z * G4H + n0 + row) * 1024 + ca * 8;
        lofsB[j] = row * 64 + ((ca ^ (row & 7)) << 3);
    }

    const int l = tid & 63, lo16 = l & 15, hi4 = l >> 4;
    const int wv = tid >> 6, wm = wv >> 1, wn = wv & 1;   // wm 0..3, wn 0..1

    f32x4 acc[4][4];
#pragma unroll
    for (int mi = 0; mi < 4; ++mi)
#pragma unroll
        for (int ni = 0; ni < 4; ++ni)
#pragma unroll
            for (int rr = 0; rr < 4; ++rr) acc[mi][ni][rr] = 0.f;

    uint4 ra[4], rb[2];
#pragma unroll
    for (int j = 0; j < 4; ++j) ra[j] = *reinterpret_cast<const uint4*>(srcA[j]);
#pragma unroll
    for (int j = 0; j < 2; ++j) rb[j] = *reinterpret_cast<const uint4*>(srcB[j]);

    const int nk = K >> 6;
    for (int kt = 0; kt < nk; ++kt) {
        __syncthreads();
#pragma unroll
        for (int j = 0; j < 4; ++j) *reinterpret_cast<uint4*>(&As[lofsA[j]]) = ra[j];
#pragma unroll
        for (int j = 0; j < 2; ++j) *reinterpret_cast<uint4*>(&Bs[lofsB[j]]) = rb[j];
        __syncthreads();
        if (kt + 1 < nk) {
#pragma unroll
            for (int j = 0; j < 4; ++j) {
                srcA[j] += 64;
                ra[j] = *reinterpret_cast<const uint4*>(srcA[j]);
            }
#pragma unroll
            for (int j = 0; j < 2; ++j) {
                srcB[j] += 64;
                rb[j] = *reinterpret_cast<const uint4*>(srcB[j]);
            }
        }
#pragma unroll
        for (int ks = 0; ks < 2; ++ks) {
            bf8v af[4], bfv[4];
#pragma unroll
            for (int mi = 0; mi < 4; ++mi) {
                int row = wm * 64 + mi * 16 + lo16;
                int c = ks * 4 + hi4;
                af[mi] = *reinterpret_cast<const bf8v*>(&As[row * 64 + ((c ^ (row & 7)) << 3)]);
            }
#pragma unroll
            for (int ni = 0; ni < 4; ++ni) {
                int row = wn * 64 + ni * 16 + lo16;
                int c = ks * 4 + hi4;
                bfv[ni] = *reinterpret_cast<const bf8v*>(&Bs[row * 64 + ((c ^ (row & 7)) << 3)]);
            }
#pragma unroll
            for (int mi = 0; mi < 4; ++mi)
#pragma unroll
                for (int ni = 0; ni < 4; ++ni)
                    acc[mi][ni] = __builtin_amdgcn_mfma_f32_16x16x32_bf16(
                        af[mi], bfv[ni], acc[mi][ni], 0, 0, 0);
        }
    }

    // ---- epilogue: two 128-row bounce passes, contiguous [b][u*4+g] writes ----
    float bv[4];
#pragma unroll
    for (int ni = 0; ni < 4; ++ni) {
        int np = n0 + wn * 64 + ni * 16 + lo16;      // interleaved col
        int raw = (np & 3) * 512 + (np >> 2);        // raw TF bias index g*512+u
        bv[ni] = bias[raw];
    }
#pragma unroll
    for (int h = 0; h < 2; ++h) {
        __syncthreads();
        if ((wm >> 1) == h) {
#pragma unroll
            for (int mi = 0; mi < 4; ++mi)
#pragma unroll
                for (int ni = 0; ni < 4; ++ni)
#pragma unroll
                    for (int rr = 0; rr < 4; ++rr) {
                        int m = (wm & 1) * 64 + mi * 16 + hi4 * 4 + rr;   // 0..127
                        int n = wn * 64 + ni * 16 + lo16;
                        smem[m * 132 + n] = f2us(acc[mi][ni][rr] + bv[ni]);
                    }
        }
        __syncthreads();
        {
            int row = tid >> 2;
            int cs  = (tid & 3) * 32;
            int m = m0 + h * 128 + row;
            int tt = m >> 6, b = m & 63;
            const unsigned short* src = smem + row * 132 + cs;
            bf16* gout = G4 + (((size_t)z * S_LEN + tt) * 64 + b) * G4H + n0 + cs;
#pragma unroll
            for (int j = 0; j < 8; ++j)
                *reinterpret_cast<ull*>(gout + j * 4) =
                    *reinterpret_cast<const ull*>(src + j * 4);
        }
    }
}

// ---------------- persistent MFMA LSTM recurrence — slot-per-step dataflow -------------
// R12 geometry (32 blocks = 2d x 2bh x 8cg; 512 thr; persistent AGPR weight frags;
// LDS-staged h; coalesced 8B bounce stores) with the flag barrier REPLACED by
// slot-per-timestep data polling: hseq[t][d][b][u] is written once (8B atomic stores,
// fire-and-forget), pre-memset to 0xFFFF (bf16 NaN, unreachable). Consumers issue their
// 8 loads and retry only sentinel words — ONE MALL RTT on the critical path instead of
// two (flag + data), no vmcnt drain, 2 barriers/step.
__global__ __launch_bounds__(512, 1)
void lstm_seq(const bf16* __restrict__ G4, const bf16* __restrict__ whTb,
              const int* __restrict__ lengths, unsigned short* __restrict__ hseq,
              bf16* __restrict__ hcat)
{
    __shared__ __align__(16) unsigned short hl[32 * 512];    // 32KB h tile (swizzled)
    __shared__ __align__(16) unsigned short hout[32 * 64];   // 4KB store bounce

    const int bx = blockIdx.x;          // 0..31
    const int d  = bx >> 4;
    const int bh = (bx >> 3) & 1;
    const int cg = bx & 7;
    const int tid = threadIdx.x;        // 0..511
    const int w = tid >> 6, l = tid & 63;
    const int lo16 = l & 15, hi4 = l >> 4;
    const int u0 = cg * 64 + w * 8;

    // ---- persistent weight A-frags: row lo16 -> (u_loc=lo16>>2, g=lo16&3) ----
    bf8v afr[2][16];
#pragma unroll
    for (int mt = 0; mt < 2; ++mt) {
        const bf16* wr = whTb + (((size_t)d * 512 + u0 + mt * 4 + (lo16 >> 2)) * 4
                                 + (lo16 & 3)) * 512 + hi4 * 8;
#pragma unroll
        for (int kt = 0; kt < 16; ++kt)
            afr[mt][kt] = *reinterpret_cast<const bf8v*>(wr + kt * 32);
    }

    int len_[2];
    float c_st[2][2], h_st[2][2];
#pragma unroll
    for (int nt = 0; nt < 2; ++nt) {
        len_[nt] = lengths[bh * 32 + nt * 16 + lo16];
#pragma unroll
        for (int mt = 0; mt < 2; ++mt) { c_st[mt][nt] = 0.f; h_st[mt][nt] = 0.f; }
    }

    for (int t = 0; t < S_LEN; ++t) {
        // ---- G loads early (stable data) ----
        ull gv[2][2];
#pragma unroll
        for (int mt = 0; mt < 2; ++mt)
#pragma unroll
            for (int nt = 0; nt < 2; ++nt) {
                int b = bh * 32 + nt * 16 + lo16;
                int u = u0 + mt * 4 + hi4;
                gv[mt][nt] = *reinterpret_cast<const ull*>(
                    G4 + (((size_t)(d * S_LEN + t)) * 64 + b) * G4H + u * 4);
            }

        // ---- h_t: issue 8 coalesced 8B loads, retry sentinel words only ----
        const ull* hsrc = reinterpret_cast<const ull*>(
            hseq + ((size_t)(t * 2 + d) * 64 + bh * 32) * 512);
        ull pv[8];
#pragma unroll
        for (int i = 0; i < 8; ++i)
            pv[i] = __hip_atomic_load(hsrc + i * 512 + tid,
                                      __ATOMIC_RELAXED, __HIP_MEMORY_SCOPE_AGENT);
#pragma unroll
        for (int i = 0; i < 8; ++i) {
            while (__builtin_expect((pv[i] & 0xFFFFull) == 0xFFFFull, 0)) {
                __builtin_amdgcn_s_sleep(1);
                pv[i] = __hip_atomic_load(hsrc + i * 512 + tid,
                                          __ATOMIC_RELAXED, __HIP_MEMORY_SCOPE_AGENT);
            }
        }

        // ---- stage into LDS (WAR vs prior MFMA protected by barB(t-1) rendezvous) ----
#pragma unroll
        for (int i = 0; i < 8; ++i) {
            int wd_ = i * 512 + tid;     // 8B word: bl = wd>>7, r = wd&127
            int bl = wd_ >> 7, r = wd_ & 127;
            int c = r >> 1, half = r & 1;
            *reinterpret_cast<ull*>(&hl[bl * 512 + ((c ^ (bl & 7)) << 3) + (half << 2)]) = pv[i];
        }
        __syncthreads();                 // barA: hl complete

        // ---- acc init from G4 (reg g = gate) ----
        f32x4 acc[2][2];
#pragma unroll
        for (int mt = 0; mt < 2; ++mt)
#pragma unroll
            for (int nt = 0; nt < 2; ++nt) {
                const unsigned short* gs = reinterpret_cast<const unsigned short*>(&gv[mt][nt]);
                f32x4 av;
#pragma unroll
                for (int g = 0; g < 4; ++g) av[g] = us2f(gs[g]);
                acc[mt][nt] = av;
            }

        // ---- MFMA: 16 kt x (2 LDS B-frags + 4 mfma), weights in regs ----
#pragma unroll
        for (int kt = 0; kt < 16; ++kt) {
            bf8v bfv[2];
#pragma unroll
            for (int nt = 0; nt < 2; ++nt) {
                int bl = nt * 16 + lo16;
                int c  = kt * 4 + hi4;
                bfv[nt] = *reinterpret_cast<const bf8v*>(
                    &hl[bl * 512 + ((c ^ (bl & 7)) << 3)]);
            }
#pragma unroll
            for (int mt = 0; mt < 2; ++mt)
#pragma unroll
                for (int nt = 0; nt < 2; ++nt)
                    acc[mt][nt] = __builtin_amdgcn_mfma_f32_16x16x32_bf16(
                        afr[mt][kt], bfv[nt], acc[mt][nt], 0, 0, 0);
        }

        // ---- pointwise: lane owns (u,b), 4 gates in regs; write h to bounce ----
#pragma unroll
        for (int mt = 0; mt < 2; ++mt)
#pragma unroll
            for (int nt = 0; nt < 2; ++nt) {
                bool msk = (t < len_[nt]);
                float i_ = sigm(acc[mt][nt][0]);
                float j_ = tanhf(acc[mt][nt][1]);
                float f_ = sigm(acc[mt][nt][2] + 1.0f);   // FORGET_BIAS
                float o_ = sigm(acc[mt][nt][3]);
                float cn = f_ * c_st[mt][nt] + i_ * j_;
                float hn = o_ * tanhf(cn);
                if (msk) c_st[mt][nt] = cn;
                h_st[mt][nt] = msk ? hn : h_st[mt][nt];
                hout[(nt * 16 + lo16) * 64 + w * 8 + mt * 4 + hi4] = f2us(h_st[mt][nt]);
            }
        __syncthreads();                 // barB: hout complete (also orders MFMA < next stage)

        // ---- fire-and-forget h_{t+1} stores: 512 x 8B atomics (no drain, no flag) ----
        {
            int bl = tid >> 4, uq = (tid & 15) * 4;
            ull v = *reinterpret_cast<const ull*>(&hout[bl * 64 + uq]);
            unsigned short* hdst = hseq + ((size_t)((t + 1) * 2 + d) * 64
                                           + bh * 32 + bl) * 512 + cg * 64 + uq;
            __hip_atomic_store(reinterpret_cast<ull*>(hdst), v,
                               __ATOMIC_RELAXED, __HIP_MEMORY_SCOPE_AGENT);
        }

        // ---- hcat stores ----
#pragma unroll
        for (int mt = 0; mt < 2; ++mt)
#pragma unroll
            for (int nt = 0; nt < 2; ++nt) {
                int b = bh * 32 + nt * 16 + lo16;
                int u = u0 + mt * 4 + hi4;
                bool msk = (t < len_[nt]);
                int p = (d == 1 && msk) ? (len_[nt] - 1 - t) : t;
                hcat[((size_t)p * 64 + b) * TWOH + (size_t)d * 512 + u] =
                    __float2bfloat16(msk ? h_st[mt][nt] : 0.f);
            }
    }
}

// ---------------- dense + softmax: out[b][s][c] ----------------
__global__ __launch_bounds__(256)
void dense_softmax(const bf16* __restrict__ h, const float* __restrict__ wd,
                   const float* __restrict__ bd, float* __restrict__ out)
{
    __shared__ __align__(16) bf16 wdT[NCLS][1032];
    for (int i = threadIdx.x; i < TWOH * NCLS; i += 256) {
        int k = i / NCLS, c = i % NCLS;    // wd[k][c]
        wdT[c][k] = __float2bfloat16(wd[i]);
    }
    __syncthreads();
    const int c  = threadIdx.x & 31;
    const int rl = threadIdx.x >> 5;
#pragma unroll 1
    for (int pass = 0; pass < 8; ++pass) {
        int r = blockIdx.x * 64 + pass * 8 + rl;   // r = s*BATCH + b
        const bf16* hrow = h + (size_t)r * TWOH;
        float acc = -1e30f;
        if (c < NCLS) {
            acc = 0.f;
            for (int k = 0; k < TWOH; k += 8) {
                uint4 hv = *reinterpret_cast<const uint4*>(hrow + k);
                uint4 wv = *reinterpret_cast<const uint4*>(&wdT[c][k]);
                const unsigned short* hs  = reinterpret_cast<const unsigned short*>(&hv);
                const unsigned short* wsp = reinterpret_cast<const unsigned short*>(&wv);
#pragma unroll
                for (int j = 0; j < 8; ++j) acc += us2f(hs[j]) * us2f(wsp[j]);
            }
            acc += bd[c];
        }
        float mx = acc;
#pragma unroll
        for (int o = 16; o; o >>= 1) mx = fmaxf(mx, __shfl_xor(mx, o, 32));
        float e = (c < NCLS) ? __expf(acc - mx) : 0.f;
        float sm = e;
#pragma unroll
        for (int o = 16; o; o >>= 1) sm += __shfl_xor(sm, o, 32);
        if (c < NCLS) {
            int s = r >> 6, b = r & 63;
            out[((size_t)b * S_LEN + s) * NCLS + c] = e / sm;
        }
    }
}

extern "C" void kernel_launch(void* const* d_in, const int* in_sizes, int n_in,
                              void* d_out, int out_size, void* d_ws, size_t ws_size,
                              hipStream_t stream)
{
    const int*   ids   = (const int*)  d_in[0];
    const int*   lens  = (const int*)  d_in[1];
    const float* emb   = (const float*)d_in[2];
    const float* w_fw0 = (const float*)d_in[3];
    const float* b_fw0 = (const float*)d_in[4];
    const float* w_bw0 = (const float*)d_in[5];
    const float* b_bw0 = (const float*)d_in[6];
    const float* w_fw1 = (const float*)d_in[7];
    const float* b_fw1 = (const float*)d_in[8];
    const float* w_bw1 = (const float*)d_in[9];
    const float* b_bw1 = (const float*)d_in[10];
    const float* wd    = (const float*)d_in[11];
    const float* bd    = (const float*)d_in[12];
    float* out = (float*)d_out;

    char* ws = (char*)d_ws;
    size_t off = 0;
    auto alloc = [&](size_t bytes) {
        void* p = ws + off;
        off += (bytes + 255) & ~(size_t)255;
        return p;
    };
    // ws budget is 256 MiB (R15 post-mortem). Total here = 253.9 MB.
    const size_t hseq_bytes = (size_t)(S_LEN + 1) * 2 * BATCH * HID * 2;  // 33.69 MB
    bf16*  x      = (bf16*) alloc((size_t)S_LEN * BATCH * EPAD * 2);      // 10.49 MB
    bf16*  G4     = (bf16*) alloc((size_t)2 * S_LEN * BATCH * G4H * 2);   // 134.2 MB
    bf16*  hcat0  = (bf16*) alloc((size_t)S_LEN * BATCH * TWOH * 2);      // 33.55 MB
    bf16*  hcat1  = (bf16*) alloc((size_t)S_LEN * BATCH * TWOH * 2);      // 33.55 MB
    bf16*  whTb   = (bf16*) alloc((size_t)4 * 512 * 4 * 512 * 2);         //  8.39 MB
    // scratch union: per-layer wxTb (8.39 MB) DURING gates, then hseq (33.69 MB)
    // DURING lstm — never live simultaneously (stream-ordered).
    void*  scratch = alloc(hseq_bytes);                                    // 33.69 MB

    embed_kernel<<<S_LEN * BATCH, 128, 0, stream>>>(ids, emb, x);
    wtrans_kernel<<<dim3(16, 64, 4), dim3(32, 32), 0, stream>>>(w_fw0, w_bw0, w_fw1, w_bw1, whTb);

    for (int layer = 0; layer < 2; ++layer) {
        const bf16* Ain   = layer ? hcat0 : x;
        int strideA       = layer ? TWOH : EPAD;
        int K             = layer ? 1024 : EPAD;
        const float* Wf   = layer ? w_fw1 : w_fw0;
        const float* Wb   = layer ? w_bw1 : w_bw0;
        int D             = layer ? TWOH : EMB;
        const float* bfp  = layer ? b_fw1 : b_fw0;
        const float* bbp  = layer ? b_bw1 : b_bw0;
        bf16* hcat        = layer ? hcat1 : hcat0;

        // phase 1: scratch = wxTb for this layer
        wxtrans_kernel<<<dim3(32, 64, 2), dim3(32, 32), 0, stream>>>(Wf, Wb, D, (bf16*)scratch);
        gates_mfma<<<dim3(64, 16, 2), 512, 0, stream>>>(
            Ain, strideA, K, (const bf16*)scratch, bfp, bbp, lens, G4);

        // phase 2: scratch = hseq (sentinel-init all slots, zero slot 0)
        hipMemsetAsync(scratch, 0xFF, hseq_bytes, stream);
        hipMemsetAsync(scratch, 0x00, (size_t)2 * BATCH * HID * 2, stream);

        const bf16*  Gp   = G4;
        const bf16*  whp  = whTb + (size_t)layer * 2 * 512 * 4 * 512;
        const int*   lnp  = lens;
        unsigned short* hsp = (unsigned short*)scratch;
        bf16*        hcp  = hcat;
        void* args[5] = { &Gp, &whp, &lnp, &hsp, &hcp };
        hipLaunchCooperativeKernel(lstm_seq, dim3(32), dim3(512), args, 0, stream);
    }
    dense_softmax<<<256, 256, 0, stream>>>(hcat1, wd, bd, out);

    (void)in_sizes; (void)n_in; (void)out_size; (void)ws_size;
}

// Round 17
// 3510.397 us; speedup vs baseline: 1.1823x; 1.0180x over previous
//
#include <hip/hip_runtime.h>
#include <hip/hip_bf16.h>

#define S_LEN 256
#define BATCH 64
#define EMB   300
#define EPAD  320
#define HID   512
#define G4H   2048
#define NCLS  25
#define TWOH  1024

using bf16 = __hip_bfloat16;
typedef short bf8v __attribute__((ext_vector_type(8)));   // 8 bf16 in 4 VGPRs
typedef float f32x4 __attribute__((ext_vector_type(4)));
typedef unsigned long long ull;

__device__ __forceinline__ float us2f(unsigned short u) {
    union { unsigned int i; float f; } v; v.i = ((unsigned int)u) << 16; return v.f;
}
__device__ __forceinline__ unsigned short f2us(float f) {
    union { bf16 v; unsigned short s; } cv; cv.v = __float2bfloat16(f); return cv.s;
}
__device__ __forceinline__ float sigm(float x) { return 1.f / (1.f + __expf(-x)); }

// ---------------- embedding gather: x[t][b][e] (bf16, padded to EPAD) ----------------
__global__ void embed_kernel(const int* __restrict__ ids,
                             const float* __restrict__ emb,
                             bf16* __restrict__ x)
{
    int r = blockIdx.x;            // r = t*BATCH + b
    int t = r >> 6, b = r & 63;
    int id = ids[b * S_LEN + t];
    const float* src = emb + (size_t)id * EMB;
    bf16* dst = x + (size_t)r * EPAD;
    for (int e = threadIdx.x; e < EPAD; e += blockDim.x) {
        float v = (e < EMB) ? src[e] : 0.f;
        dst[e] = __float2bfloat16(v);
    }
}

// ------- transpose recurrent weights to bf16: whTb[wl][u][g][k] = W[D+k][g*512+u] -------
__global__ void wtrans_kernel(const float* __restrict__ w_fw0, const float* __restrict__ w_bw0,
                              const float* __restrict__ w_fw1, const float* __restrict__ w_bw1,
                              bf16* __restrict__ whTb)
{
    __shared__ float tile[32][33];
    int wl = blockIdx.z;
    const float* W; int D;
    if (wl == 0)      { W = w_fw0; D = EMB; }
    else if (wl == 1) { W = w_bw0; D = EMB; }
    else if (wl == 2) { W = w_fw1; D = TWOH; }
    else              { W = w_bw1; D = TWOH; }
    int k0 = blockIdx.x * 32, n0 = blockIdx.y * 32;
    int tx = threadIdx.x, ty = threadIdx.y;
    tile[ty][tx] = W[(size_t)(D + k0 + ty) * G4H + n0 + tx];
    __syncthreads();
    int k = k0 + tx;
    int n = n0 + ty;                  // raw TF col: n = g*512 + u
    int u = n & 511, g = n >> 9;
    whTb[(((size_t)wl * 512 + u) * 4 + g) * 512 + k] = __float2bfloat16(tile[tx][ty]);
}

// --- per-layer transpose of INPUT weights, gate-interleaved cols: wxTb[z][u*4+g][k] ---
__global__ void wxtrans_kernel(const float* __restrict__ w_fw, const float* __restrict__ w_bw,
                               int D, bf16* __restrict__ wxTb)
{
    __shared__ float tile[32][33];
    int z = blockIdx.z;
    const float* W = z ? w_bw : w_fw;
    int k0 = blockIdx.x * 32, n0 = blockIdx.y * 32;
    int tx = threadIdx.x, ty = threadIdx.y;
    float v = (k0 + ty < D) ? W[(size_t)(k0 + ty) * G4H + n0 + tx] : 0.f;
    tile[ty][tx] = v;
    __syncthreads();
    int n = n0 + ty;                  // raw col -> interleaved row u*4+g
    int u = n & 511, g = n >> 9;
    wxTb[((size_t)z * G4H + (u * 4 + g)) * 1024 + k0 + tx] = __float2bfloat16(tile[tx][ty]);
}

// -------- MFMA input-gate GEMM: G4[z][t][b][u*4+g] = gather(A) @ Wx + bias --------
// 256x128x64 tile, 8 waves (4x2), 512 threads, reg-staged LDS with 16B-chunk XOR swizzle.
__global__ __launch_bounds__(512)
void gates_mfma(const bf16* __restrict__ A, int strideA, int K,
                const bf16* __restrict__ wxTb,
                const float* __restrict__ b_fw, const float* __restrict__ b_bw,
                const int* __restrict__ lengths,
                bf16* __restrict__ G4)
{
    const int z  = blockIdx.z;
    const int m0 = blockIdx.x * 256;
    const int n0 = blockIdx.y * 128;
    const int tid = threadIdx.x;        // 0..511
    const float* bias = z ? b_bw : b_fw;

    __shared__ __align__(16) unsigned short smem[24576];  // As 256x64 | Bs 128x64 (48KB)
    unsigned short* As = smem;
    unsigned short* Bs = smem + 16384;

    const int ca = tid & 7;
    const bf16* srcA[4];
    const bf16* srcB[2];
    int lofsA[4], lofsB[2];
#pragma unroll
    for (int j = 0; j < 4; ++j) {
        int row = j * 64 + (tid >> 3);
        int r = m0 + row, t = r >> 6, b = r & 63;
        int st = t;
        if (z) { int len = lengths[b]; st = (t < len) ? (len - 1 - t) : t; }
        srcA[j] = A + (size_t)(st * 64 + b) * strideA + ca * 8;
        lofsA[j] = row * 64 + ((ca ^ (row & 7)) << 3);
    }
#pragma unroll
    for (int j = 0; j < 2; ++j) {
        int row = j * 64 + (tid >> 3);
        srcB[j] = wxTb + ((size_t)z * G4H + n0 + row) * 1024 + ca * 8;
        lofsB[j] = row * 64 + ((ca ^ (row & 7)) << 3);
    }

    const int l = tid & 63, lo16 = l & 15, hi4 = l >> 4;
    const int wv = tid >> 6, wm = wv >> 1, wn = wv & 1;   // wm 0..3, wn 0..1

    f32x4 acc[4][4];
#pragma unroll
    for (int mi = 0; mi < 4; ++mi)
#pragma unroll
        for (int ni = 0; ni < 4; ++ni)
#pragma unroll
            for (int rr = 0; rr < 4; ++rr) acc[mi][ni][rr] = 0.f;

    uint4 ra[4], rb[2];
#pragma unroll
    for (int j = 0; j < 4; ++j) ra[j] = *reinterpret_cast<const uint4*>(srcA[j]);
#pragma unroll
    for (int j = 0; j < 2; ++j) rb[j] = *reinterpret_cast<const uint4*>(srcB[j]);

    const int nk = K >> 6;
    for (int kt = 0; kt < nk; ++kt) {
        __syncthreads();
#pragma unroll
        for (int j = 0; j < 4; ++j) *reinterpret_cast<uint4*>(&As[lofsA[j]]) = ra[j];
#pragma unroll
        for (int j = 0; j < 2; ++j) *reinterpret_cast<uint4*>(&Bs[lofsB[j]]) = rb[j];
        __syncthreads();
        if (kt + 1 < nk) {
#pragma unroll
            for (int j = 0; j < 4; ++j) {
                srcA[j] += 64;
                ra[j] = *reinterpret_cast<const uint4*>(srcA[j]);
            }
#pragma unroll
            for (int j = 0; j < 2; ++j) {
                srcB[j] += 64;
                rb[j] = *reinterpret_cast<const uint4*>(srcB[j]);
            }
        }
#pragma unroll
        for (int ks = 0; ks < 2; ++ks) {
            bf8v af[4], bfv[4];
#pragma unroll
            for (int mi = 0; mi < 4; ++mi) {
                int row = wm * 64 + mi * 16 + lo16;
                int c = ks * 4 + hi4;
                af[mi] = *reinterpret_cast<const bf8v*>(&As[row * 64 + ((c ^ (row & 7)) << 3)]);
            }
#pragma unroll
            for (int ni = 0; ni < 4; ++ni) {
                int row = wn * 64 + ni * 16 + lo16;
                int c = ks * 4 + hi4;
                bfv[ni] = *reinterpret_cast<const bf8v*>(&Bs[row * 64 + ((c ^ (row & 7)) << 3)]);
            }
#pragma unroll
            for (int mi = 0; mi < 4; ++mi)
#pragma unroll
                for (int ni = 0; ni < 4; ++ni)
                    acc[mi][ni] = __builtin_amdgcn_mfma_f32_16x16x32_bf16(
                        af[mi], bfv[ni], acc[mi][ni], 0, 0, 0);
        }
    }

    // ---- epilogue: two 128-row bounce passes, contiguous [b][u*4+g] writes ----
    float bv[4];
#pragma unroll
    for (int ni = 0; ni < 4; ++ni) {
        int np = n0 + wn * 64 + ni * 16 + lo16;      // interleaved col
        int raw = (np & 3) * 512 + (np >> 2);        // raw TF bias index g*512+u
        bv[ni] = bias[raw];
    }
#pragma unroll
    for (int h = 0; h < 2; ++h) {
        __syncthreads();
        if ((wm >> 1) == h) {
#pragma unroll
            for (int mi = 0; mi < 4; ++mi)
#pragma unroll
                for (int ni = 0; ni < 4; ++ni)
#pragma unroll
                    for (int rr = 0; rr < 4; ++rr) {
                        int m = (wm & 1) * 64 + mi * 16 + hi4 * 4 + rr;   // 0..127
                        int n = wn * 64 + ni * 16 + lo16;
                        smem[m * 132 + n] = f2us(acc[mi][ni][rr] + bv[ni]);
                    }
        }
        __syncthreads();
        {
            int row = tid >> 2;
            int cs  = (tid & 3) * 32;
            int m = m0 + h * 128 + row;
            int tt = m >> 6, b = m & 63;
            const unsigned short* src = smem + row * 132 + cs;
            bf16* gout = G4 + (((size_t)z * S_LEN + tt) * 64 + b) * G4H + n0 + cs;
#pragma unroll
            for (int j = 0; j < 8; ++j)
                *reinterpret_cast<ull*>(gout + j * 4) =
                    *reinterpret_cast<const ull*>(src + j * 4);
        }
    }
}

// ---------------- persistent MFMA LSTM recurrence — slot-per-step dataflow -------------
// R16 structure. R17 change (poll only): word->producer interleave (each thread's 8
// words span the 8 producer blocks, not one) + batched parallel retry (reissue ALL
// invalid words per round, one wait) — compresses the racing-tail from up to 8 serial
// MALL RTTs per thread to ~(rounds) RTTs.
__global__ __launch_bounds__(512, 1)
void lstm_seq(const bf16* __restrict__ G4, const bf16* __restrict__ whTb,
              const int* __restrict__ lengths, unsigned short* __restrict__ hseq,
              bf16* __restrict__ hcat)
{
    __shared__ __align__(16) unsigned short hl[32 * 512];    // 32KB h tile (swizzled)
    __shared__ __align__(16) unsigned short hout[32 * 64];   // 4KB store bounce

    const int bx = blockIdx.x;          // 0..31
    const int d  = bx >> 4;
    const int bh = (bx >> 3) & 1;
    const int cg = bx & 7;
    const int tid = threadIdx.x;        // 0..511
    const int w = tid >> 6, l = tid & 63;
    const int lo16 = l & 15, hi4 = l >> 4;
    const int u0 = cg * 64 + w * 8;

    // word id for poll/stage: wd = i*16 + (tid&15) + (tid>>4)*128  (bijective, i<8)
    // -> bl = wd>>7 = tid>>4 (0..31), r = wd&127 = i*16 + (tid&15): the 8 words of a
    // thread span 8 distinct u-64-slices = 8 distinct producer blocks.
    int wdv[8];
#pragma unroll
    for (int i = 0; i < 8; ++i) wdv[i] = i * 16 + (tid & 15) + (tid >> 4) * 128;

    // ---- persistent weight A-frags: row lo16 -> (u_loc=lo16>>2, g=lo16&3) ----
    bf8v afr[2][16];
#pragma unroll
    for (int mt = 0; mt < 2; ++mt) {
        const bf16* wr = whTb + (((size_t)d * 512 + u0 + mt * 4 + (lo16 >> 2)) * 4
                                 + (lo16 & 3)) * 512 + hi4 * 8;
#pragma unroll
        for (int kt = 0; kt < 16; ++kt)
            afr[mt][kt] = *reinterpret_cast<const bf8v*>(wr + kt * 32);
    }

    int len_[2];
    float c_st[2][2], h_st[2][2];
#pragma unroll
    for (int nt = 0; nt < 2; ++nt) {
        len_[nt] = lengths[bh * 32 + nt * 16 + lo16];
#pragma unroll
        for (int mt = 0; mt < 2; ++mt) { c_st[mt][nt] = 0.f; h_st[mt][nt] = 0.f; }
    }

    for (int t = 0; t < S_LEN; ++t) {
        // ---- G loads early (stable data) ----
        ull gv[2][2];
#pragma unroll
        for (int mt = 0; mt < 2; ++mt)
#pragma unroll
            for (int nt = 0; nt < 2; ++nt) {
                int b = bh * 32 + nt * 16 + lo16;
                int u = u0 + mt * 4 + hi4;
                gv[mt][nt] = *reinterpret_cast<const ull*>(
                    G4 + (((size_t)(d * S_LEN + t)) * 64 + b) * G4H + u * 4);
            }

        // ---- h_t: issue 8 8B loads (one per producer), batched parallel retry ----
        const ull* hsrc = reinterpret_cast<const ull*>(
            hseq + ((size_t)(t * 2 + d) * 64 + bh * 32) * 512);
        ull pv[8];
#pragma unroll
        for (int i = 0; i < 8; ++i)
            pv[i] = __hip_atomic_load(hsrc + wdv[i],
                                      __ATOMIC_RELAXED, __HIP_MEMORY_SCOPE_AGENT);
        {
            unsigned msk = 0;
#pragma unroll
            for (int i = 0; i < 8; ++i)
                msk |= ((pv[i] & 0xFFFFull) == 0xFFFFull) ? (1u << i) : 0u;
            while (__builtin_expect(msk != 0u, 0)) {
                __builtin_amdgcn_s_sleep(1);
#pragma unroll
                for (int i = 0; i < 8; ++i)
                    if (msk & (1u << i))
                        pv[i] = __hip_atomic_load(hsrc + wdv[i],
                                                  __ATOMIC_RELAXED, __HIP_MEMORY_SCOPE_AGENT);
                unsigned nm = 0;
#pragma unroll
                for (int i = 0; i < 8; ++i)
                    if (msk & (1u << i))
                        nm |= ((pv[i] & 0xFFFFull) == 0xFFFFull) ? (1u << i) : 0u;
                msk = nm;
            }
        }

        // ---- stage into LDS (WAR vs prior MFMA protected by barB(t-1) rendezvous) ----
#pragma unroll
        for (int i = 0; i < 8; ++i) {
            int bl = wdv[i] >> 7, r = wdv[i] & 127;
            int c = r >> 1, half = r & 1;
            *reinterpret_cast<ull*>(&hl[bl * 512 + ((c ^ (bl & 7)) << 3) + (half << 2)]) = pv[i];
        }
        __syncthreads();                 // barA: hl complete

        // ---- acc init from G4 (reg g = gate) ----
        f32x4 acc[2][2];
#pragma unroll
        for (int mt = 0; mt < 2; ++mt)
#pragma unroll
            for (int nt = 0; nt < 2; ++nt) {
                const unsigned short* gs = reinterpret_cast<const unsigned short*>(&gv[mt][nt]);
                f32x4 av;
#pragma unroll
                for (int g = 0; g < 4; ++g) av[g] = us2f(gs[g]);
                acc[mt][nt] = av;
            }

        // ---- MFMA: 16 kt x (2 LDS B-frags + 4 mfma), weights in regs ----
#pragma unroll
        for (int kt = 0; kt < 16; ++kt) {
            bf8v bfv[2];
#pragma unroll
            for (int nt = 0; nt < 2; ++nt) {
                int bl = nt * 16 + lo16;
                int c  = kt * 4 + hi4;
                bfv[nt] = *reinterpret_cast<const bf8v*>(
                    &hl[bl * 512 + ((c ^ (bl & 7)) << 3)]);
            }
#pragma unroll
            for (int mt = 0; mt < 2; ++mt)
#pragma unroll
                for (int nt = 0; nt < 2; ++nt)
                    acc[mt][nt] = __builtin_amdgcn_mfma_f32_16x16x32_bf16(
                        afr[mt][kt], bfv[nt], acc[mt][nt], 0, 0, 0);
        }

        // ---- pointwise: lane owns (u,b), 4 gates in regs; write h to bounce ----
#pragma unroll
        for (int mt = 0; mt < 2; ++mt)
#pragma unroll
            for (int nt = 0; nt < 2; ++nt) {
                bool msk = (t < len_[nt]);
                float i_ = sigm(acc[mt][nt][0]);
                float j_ = tanhf(acc[mt][nt][1]);
                float f_ = sigm(acc[mt][nt][2] + 1.0f);   // FORGET_BIAS
                float o_ = sigm(acc[mt][nt][3]);
                float cn = f_ * c_st[mt][nt] + i_ * j_;
                float hn = o_ * tanhf(cn);
                if (msk) c_st[mt][nt] = cn;
                h_st[mt][nt] = msk ? hn : h_st[mt][nt];
                hout[(nt * 16 + lo16) * 64 + w * 8 + mt * 4 + hi4] = f2us(h_st[mt][nt]);
            }
        __syncthreads();                 // barB: hout complete (also orders MFMA < next stage)

        // ---- fire-and-forget h_{t+1} stores: 512 x 8B atomics (no drain, no flag) ----
        {
            int bl = tid >> 4, uq = (tid & 15) * 4;
            ull v = *reinterpret_cast<const ull*>(&hout[bl * 64 + uq]);
            unsigned short* hdst = hseq + ((size_t)((t + 1) * 2 + d) * 64
                                           + bh * 32 + bl) * 512 + cg * 64 + uq;
            __hip_atomic_store(reinterpret_cast<ull*>(hdst), v,
                               __ATOMIC_RELAXED, __HIP_MEMORY_SCOPE_AGENT);
        }

        // ---- hcat stores ----
#pragma unroll
        for (int mt = 0; mt < 2; ++mt)
#pragma unroll
            for (int nt = 0; nt < 2; ++nt) {
                int b = bh * 32 + nt * 16 + lo16;
                int u = u0 + mt * 4 + hi4;
                bool msk = (t < len_[nt]);
                int p = (d == 1 && msk) ? (len_[nt] - 1 - t) : t;
                hcat[((size_t)p * 64 + b) * TWOH + (size_t)d * 512 + u] =
                    __float2bfloat16(msk ? h_st[mt][nt] : 0.f);
            }
    }
}

// ---------------- dense + softmax: out[b][s][c] ----------------
__global__ __launch_bounds__(256)
void dense_softmax(const bf16* __restrict__ h, const float* __restrict__ wd,
                   const float* __restrict__ bd, float* __restrict__ out)
{
    __shared__ __align__(16) bf16 wdT[NCLS][1032];
    for (int i = threadIdx.x; i < TWOH * NCLS; i += 256) {
        int k = i / NCLS, c = i % NCLS;    // wd[k][c]
        wdT[c][k] = __float2bfloat16(wd[i]);
    }
    __syncthreads();
    const int c  = threadIdx.x & 31;
    const int rl = threadIdx.x >> 5;
#pragma unroll 1
    for (int pass = 0; pass < 8; ++pass) {
        int r = blockIdx.x * 64 + pass * 8 + rl;   // r = s*BATCH + b
        const bf16* hrow = h + (size_t)r * TWOH;
        float acc = -1e30f;
        if (c < NCLS) {
            acc = 0.f;
            for (int k = 0; k < TWOH; k += 8) {
                uint4 hv = *reinterpret_cast<const uint4*>(hrow + k);
                uint4 wv = *reinterpret_cast<const uint4*>(&wdT[c][k]);
                const unsigned short* hs  = reinterpret_cast<const unsigned short*>(&hv);
                const unsigned short* wsp = reinterpret_cast<const unsigned short*>(&wv);
#pragma unroll
                for (int j = 0; j < 8; ++j) acc += us2f(hs[j]) * us2f(wsp[j]);
            }
            acc += bd[c];
        }
        float mx = acc;
#pragma unroll
        for (int o = 16; o; o >>= 1) mx = fmaxf(mx, __shfl_xor(mx, o, 32));
        float e = (c < NCLS) ? __expf(acc - mx) : 0.f;
        float sm = e;
#pragma unroll
        for (int o = 16; o; o >>= 1) sm += __shfl_xor(sm, o, 32);
        if (c < NCLS) {
            int s = r >> 6, b = r & 63;
            out[((size_t)b * S_LEN + s) * NCLS + c] = e / sm;
        }
    }
}

extern "C" void kernel_launch(void* const* d_in, const int* in_sizes, int n_in,
                              void* d_out, int out_size, void* d_ws, size_t ws_size,
                              hipStream_t stream)
{
    const int*   ids   = (const int*)  d_in[0];
    const int*   lens  = (const int*)  d_in[1];
    const float* emb   = (const float*)d_in[2];
    const float* w_fw0 = (const float*)d_in[3];
    const float* b_fw0 = (const float*)d_in[4];
    const float* w_bw0 = (const float*)d_in[5];
    const float* b_bw0 = (const float*)d_in[6];
    const float* w_fw1 = (const float*)d_in[7];
    const float* b_fw1 = (const float*)d_in[8];
    const float* w_bw1 = (const float*)d_in[9];
    const float* b_bw1 = (const float*)d_in[10];
    const float* wd    = (const float*)d_in[11];
    const float* bd    = (const float*)d_in[12];
    float* out = (float*)d_out;

    char* ws = (char*)d_ws;
    size_t off = 0;
    auto alloc = [&](size_t bytes) {
        void* p = ws + off;
        off += (bytes + 255) & ~(size_t)255;
        return p;
    };
    // ws budget 256 MiB (R15 post-mortem). Total = 253.9 MB.
    const size_t hseq_bytes = (size_t)(S_LEN + 1) * 2 * BATCH * HID * 2;  // 33.69 MB
    bf16*  x      = (bf16*) alloc((size_t)S_LEN * BATCH * EPAD * 2);      // 10.49 MB
    bf16*  G4     = (bf16*) alloc((size_t)2 * S_LEN * BATCH * G4H * 2);   // 134.2 MB
    bf16*  hcat0  = (bf16*) alloc((size_t)S_LEN * BATCH * TWOH * 2);      // 33.55 MB
    bf16*  hcat1  = (bf16*) alloc((size_t)S_LEN * BATCH * TWOH * 2);      // 33.55 MB
    bf16*  whTb   = (bf16*) alloc((size_t)4 * 512 * 4 * 512 * 2);         //  8.39 MB
    // scratch union: per-layer wxTb (8.39 MB) DURING gates, then hseq (33.69 MB)
    // DURING lstm — never live simultaneously (stream-ordered).
    void*  scratch = alloc(hseq_bytes);                                    // 33.69 MB

    embed_kernel<<<S_LEN * BATCH, 128, 0, stream>>>(ids, emb, x);
    wtrans_kernel<<<dim3(16, 64, 4), dim3(32, 32), 0, stream>>>(w_fw0, w_bw0, w_fw1, w_bw1, whTb);

    for (int layer = 0; layer < 2; ++layer) {
        const bf16* Ain   = layer ? hcat0 : x;
        int strideA       = layer ? TWOH : EPAD;
        int K             = layer ? 1024 : EPAD;
        const float* Wf   = layer ? w_fw1 : w_fw0;
        const float* Wb   = layer ? w_bw1 : w_bw0;
        int D             = layer ? TWOH : EMB;
        const float* bfp  = layer ? b_fw1 : b_fw0;
        const float* bbp  = layer ? b_bw1 : b_bw0;
        bf16* hcat        = layer ? hcat1 : hcat0;

        // phase 1: scratch = wxTb for this layer
        wxtrans_kernel<<<dim3(32, 64, 2), dim3(32, 32), 0, stream>>>(Wf, Wb, D, (bf16*)scratch);
        gates_mfma<<<dim3(64, 16, 2), 512, 0, stream>>>(
            Ain, strideA, K, (const bf16*)scratch, bfp, bbp, lens, G4);

        // phase 2: scratch = hseq (sentinel-init all slots, zero slot 0)
        hipMemsetAsync(scratch, 0xFF, hseq_bytes, stream);
        hipMemsetAsync(scratch, 0x00, (size_t)2 * BATCH * HID * 2, stream);

        const bf16*  Gp   = G4;
        const bf16*  whp  = whTb + (size_t)layer * 2 * 512 * 4 * 512;
        const int*   lnp  = lens;
        unsigned short* hsp = (unsigned short*)scratch;
        bf16*        hcp  = hcat;
        void* args[5] = { &Gp, &whp, &lnp, &hsp, &hcp };
        hipLaunchCooperativeKernel(lstm_seq, dim3(32), dim3(512), args, 0, stream);
    }
    dense_softmax<<<256, 256, 0, stream>>>(hcat1, wd, bd, out);

    (void)in_sizes; (void)n_in; (void)out_size; (void)ws_size;
}

// Round 18
// 3040.895 us; speedup vs baseline: 1.3649x; 1.1544x over previous
//
#include <hip/hip_runtime.h>
#include <hip/hip_bf16.h>

#define S_LEN 256
#define BATCH 64
#define EMB   300
#define EPAD  320
#define HID   512
#define G4H   2048
#define NCLS  25
#define TWOH  1024

using bf16 = __hip_bfloat16;
typedef short bf8v __attribute__((ext_vector_type(8)));   // 8 bf16 in 4 VGPRs
typedef float f32x4 __attribute__((ext_vector_type(4)));
typedef unsigned long long ull;

#define GLOAD_LDS16(g, l)                                                     \
    __builtin_amdgcn_global_load_lds(                                         \
        (const __attribute__((address_space(1))) void*)(g),                   \
        (__attribute__((address_space(3))) void*)(l), 16, 0, 0)

__device__ __forceinline__ float us2f(unsigned short u) {
    union { unsigned int i; float f; } v; v.i = ((unsigned int)u) << 16; return v.f;
}
__device__ __forceinline__ unsigned short f2us(float f) {
    union { bf16 v; unsigned short s; } cv; cv.v = __float2bfloat16(f); return cv.s;
}
__device__ __forceinline__ float sigm(float x) { return 1.f / (1.f + __expf(-x)); }

// ---------------- embedding gather: x[t][b][e] (bf16, padded to EPAD) ----------------
__global__ void embed_kernel(const int* __restrict__ ids,
                             const float* __restrict__ emb,
                             bf16* __restrict__ x)
{
    int r = blockIdx.x;            // r = t*BATCH + b
    int t = r >> 6, b = r & 63;
    int id = ids[b * S_LEN + t];
    const float* src = emb + (size_t)id * EMB;
    bf16* dst = x + (size_t)r * EPAD;
    for (int e = threadIdx.x; e < EPAD; e += blockDim.x) {
        float v = (e < EMB) ? src[e] : 0.f;
        dst[e] = __float2bfloat16(v);
    }
}

// ------- transpose recurrent weights to bf16: whTb[wl][u][g][k] = W[D+k][g*512+u] -------
__global__ void wtrans_kernel(const float* __restrict__ w_fw0, const float* __restrict__ w_bw0,
                              const float* __restrict__ w_fw1, const float* __restrict__ w_bw1,
                              bf16* __restrict__ whTb)
{
    __shared__ float tile[32][33];
    int wl = blockIdx.z;
    const float* W; int D;
    if (wl == 0)      { W = w_fw0; D = EMB; }
    else if (wl == 1) { W = w_bw0; D = EMB; }
    else if (wl == 2) { W = w_fw1; D = TWOH; }
    else              { W = w_bw1; D = TWOH; }
    int k0 = blockIdx.x * 32, n0 = blockIdx.y * 32;
    int tx = threadIdx.x, ty = threadIdx.y;
    tile[ty][tx] = W[(size_t)(D + k0 + ty) * G4H + n0 + tx];
    __syncthreads();
    int k = k0 + tx;
    int n = n0 + ty;                  // raw TF col: n = g*512 + u
    int u = n & 511, g = n >> 9;
    whTb[(((size_t)wl * 512 + u) * 4 + g) * 512 + k] = __float2bfloat16(tile[tx][ty]);
}

// --- per-layer transpose of INPUT weights, gate-interleaved cols: wxTb[z][u*4+g][k] ---
__global__ void wxtrans_kernel(const float* __restrict__ w_fw, const float* __restrict__ w_bw,
                               int D, bf16* __restrict__ wxTb)
{
    __shared__ float tile[32][33];
    int z = blockIdx.z;
    const float* W = z ? w_bw : w_fw;
    int k0 = blockIdx.x * 32, n0 = blockIdx.y * 32;
    int tx = threadIdx.x, ty = threadIdx.y;
    float v = (k0 + ty < D) ? W[(size_t)(k0 + ty) * G4H + n0 + tx] : 0.f;
    tile[ty][tx] = v;
    __syncthreads();
    int n = n0 + ty;                  // raw col -> interleaved row u*4+g
    int u = n & 511, g = n >> 9;
    wxTb[((size_t)z * G4H + (u * 4 + g)) * 1024 + k0 + tx] = __float2bfloat16(tile[tx][ty]);
}

// -------- MFMA input-gate GEMM: G4[z][t][b][u*4+g] = gather(A) @ Wx + bias --------
// 256x128x64 tile, 8 waves, 512 threads. R18: staging via global_load_lds width-16
// (m97 pattern): LINEAR LDS dest (wave-uniform base + lane*16B), XOR swizzle applied
// to the GLOBAL source address; read side XORs again (identity) — rule #21.
__global__ __launch_bounds__(512)
void gates_mfma(const bf16* __restrict__ A, int strideA, int K,
                const bf16* __restrict__ wxTb,
                const float* __restrict__ b_fw, const float* __restrict__ b_bw,
                const int* __restrict__ lengths,
                bf16* __restrict__ G4)
{
    const int z  = blockIdx.z;
    const int m0 = blockIdx.x * 256;
    const int n0 = blockIdx.y * 128;
    const int tid = threadIdx.x;        // 0..511
    const float* bias = z ? b_bw : b_fw;

    __shared__ __align__(16) unsigned short smem[24576];  // As 256x64 | Bs 128x64 (48KB)
    unsigned short* As = smem;
    unsigned short* Bs = smem + 16384;

    const int ca = tid & 7;
    const bf16* srcA[4];
    const bf16* srcB[2];
    unsigned short* ldsA[4];
    unsigned short* ldsB[2];
#pragma unroll
    for (int j = 0; j < 4; ++j) {
        int row = j * 64 + (tid >> 3);
        int r = m0 + row, t = r >> 6, b = r & 63;
        int st = t;
        if (z) { int len = lengths[b]; st = (t < len) ? (len - 1 - t) : t; }
        srcA[j] = A + (size_t)(st * 64 + b) * strideA + ((ca ^ (row & 7)) * 8);
        ldsA[j] = As + row * 64 + ca * 8;          // linear dest
    }
#pragma unroll
    for (int j = 0; j < 2; ++j) {
        int row = j * 64 + (tid >> 3);
        srcB[j] = wxTb + ((size_t)z * G4H + n0 + row) * 1024 + ((ca ^ (row & 7)) * 8);
        ldsB[j] = Bs + row * 64 + ca * 8;          // linear dest
    }

    const int l = tid & 63, lo16 = l & 15, hi4 = l >> 4;
    const int wv = tid >> 6, wm = wv >> 1, wn = wv & 1;   // wm 0..3, wn 0..1

    f32x4 acc[4][4];
#pragma unroll
    for (int mi = 0; mi < 4; ++mi)
#pragma unroll
        for (int ni = 0; ni < 4; ++ni)
#pragma unroll
            for (int rr = 0; rr < 4; ++rr) acc[mi][ni][rr] = 0.f;

    const int nk = K >> 6;
    for (int kt = 0; kt < nk; ++kt) {
        __syncthreads();                // WAR: prior compute done before overwrite
#pragma unroll
        for (int j = 0; j < 4; ++j) GLOAD_LDS16(srcA[j] + kt * 64, ldsA[j]);
#pragma unroll
        for (int j = 0; j < 2; ++j) GLOAD_LDS16(srcB[j] + kt * 64, ldsB[j]);
        __syncthreads();                // compiler drains vmcnt(0) before barrier
#pragma unroll
        for (int ks = 0; ks < 2; ++ks) {
            bf8v af[4], bfv[4];
#pragma unroll
            for (int mi = 0; mi < 4; ++mi) {
                int row = wm * 64 + mi * 16 + lo16;
                int c = ks * 4 + hi4;
                af[mi] = *reinterpret_cast<const bf8v*>(&As[row * 64 + ((c ^ (row & 7)) << 3)]);
            }
#pragma unroll
            for (int ni = 0; ni < 4; ++ni) {
                int row = wn * 64 + ni * 16 + lo16;
                int c = ks * 4 + hi4;
                bfv[ni] = *reinterpret_cast<const bf8v*>(&Bs[row * 64 + ((c ^ (row & 7)) << 3)]);
            }
#pragma unroll
            for (int mi = 0; mi < 4; ++mi)
#pragma unroll
                for (int ni = 0; ni < 4; ++ni)
                    acc[mi][ni] = __builtin_amdgcn_mfma_f32_16x16x32_bf16(
                        af[mi], bfv[ni], acc[mi][ni], 0, 0, 0);
        }
    }

    // ---- epilogue: two 128-row bounce passes, contiguous [b][u*4+g] writes ----
    float bv[4];
#pragma unroll
    for (int ni = 0; ni < 4; ++ni) {
        int np = n0 + wn * 64 + ni * 16 + lo16;      // interleaved col
        int raw = (np & 3) * 512 + (np >> 2);        // raw TF bias index g*512+u
        bv[ni] = bias[raw];
    }
#pragma unroll
    for (int h = 0; h < 2; ++h) {
        __syncthreads();
        if ((wm >> 1) == h) {
#pragma unroll
            for (int mi = 0; mi < 4; ++mi)
#pragma unroll
                for (int ni = 0; ni < 4; ++ni)
#pragma unroll
                    for (int rr = 0; rr < 4; ++rr) {
                        int m = (wm & 1) * 64 + mi * 16 + hi4 * 4 + rr;   // 0..127
                        int n = wn * 64 + ni * 16 + lo16;
                        smem[m * 132 + n] = f2us(acc[mi][ni][rr] + bv[ni]);
                    }
        }
        __syncthreads();
        {
            int row = tid >> 2;
            int cs  = (tid & 3) * 32;
            int m = m0 + h * 128 + row;
            int tt = m >> 6, b = m & 63;
            const unsigned short* src = smem + row * 132 + cs;
            bf16* gout = G4 + (((size_t)z * S_LEN + tt) * 64 + b) * G4H + n0 + cs;
#pragma unroll
            for (int j = 0; j < 8; ++j)
                *reinterpret_cast<ull*>(gout + j * 4) =
                    *reinterpret_cast<const ull*>(src + j * 4);
        }
    }
}

// ---------------- persistent MFMA LSTM recurrence — slot-per-step dataflow -------------
// FROZEN (R17, best measured 1306 us/layer): latency floor confirmed across three sync
// schemes. Word->producer interleaved sentinel poll, batched parallel retry.
__global__ __launch_bounds__(512, 1)
void lstm_seq(const bf16* __restrict__ G4, const bf16* __restrict__ whTb,
              const int* __restrict__ lengths, unsigned short* __restrict__ hseq,
              bf16* __restrict__ hcat)
{
    __shared__ __align__(16) unsigned short hl[32 * 512];    // 32KB h tile (swizzled)
    __shared__ __align__(16) unsigned short hout[32 * 64];   // 4KB store bounce

    const int bx = blockIdx.x;          // 0..31
    const int d  = bx >> 4;
    const int bh = (bx >> 3) & 1;
    const int cg = bx & 7;
    const int tid = threadIdx.x;        // 0..511
    const int w = tid >> 6, l = tid & 63;
    const int lo16 = l & 15, hi4 = l >> 4;
    const int u0 = cg * 64 + w * 8;

    int wdv[8];
#pragma unroll
    for (int i = 0; i < 8; ++i) wdv[i] = i * 16 + (tid & 15) + (tid >> 4) * 128;

    // ---- persistent weight A-frags: row lo16 -> (u_loc=lo16>>2, g=lo16&3) ----
    bf8v afr[2][16];
#pragma unroll
    for (int mt = 0; mt < 2; ++mt) {
        const bf16* wr = whTb + (((size_t)d * 512 + u0 + mt * 4 + (lo16 >> 2)) * 4
                                 + (lo16 & 3)) * 512 + hi4 * 8;
#pragma unroll
        for (int kt = 0; kt < 16; ++kt)
            afr[mt][kt] = *reinterpret_cast<const bf8v*>(wr + kt * 32);
    }

    int len_[2];
    float c_st[2][2], h_st[2][2];
#pragma unroll
    for (int nt = 0; nt < 2; ++nt) {
        len_[nt] = lengths[bh * 32 + nt * 16 + lo16];
#pragma unroll
        for (int mt = 0; mt < 2; ++mt) { c_st[mt][nt] = 0.f; h_st[mt][nt] = 0.f; }
    }

    for (int t = 0; t < S_LEN; ++t) {
        // ---- G loads early (stable data) ----
        ull gv[2][2];
#pragma unroll
        for (int mt = 0; mt < 2; ++mt)
#pragma unroll
            for (int nt = 0; nt < 2; ++nt) {
                int b = bh * 32 + nt * 16 + lo16;
                int u = u0 + mt * 4 + hi4;
                gv[mt][nt] = *reinterpret_cast<const ull*>(
                    G4 + (((size_t)(d * S_LEN + t)) * 64 + b) * G4H + u * 4);
            }

        // ---- h_t: issue 8 8B loads (one per producer), batched parallel retry ----
        const ull* hsrc = reinterpret_cast<const ull*>(
            hseq + ((size_t)(t * 2 + d) * 64 + bh * 32) * 512);
        ull pv[8];
#pragma unroll
        for (int i = 0; i < 8; ++i)
            pv[i] = __hip_atomic_load(hsrc + wdv[i],
                                      __ATOMIC_RELAXED, __HIP_MEMORY_SCOPE_AGENT);
        {
            unsigned msk = 0;
#pragma unroll
            for (int i = 0; i < 8; ++i)
                msk |= ((pv[i] & 0xFFFFull) == 0xFFFFull) ? (1u << i) : 0u;
            while (__builtin_expect(msk != 0u, 0)) {
                __builtin_amdgcn_s_sleep(1);
#pragma unroll
                for (int i = 0; i < 8; ++i)
                    if (msk & (1u << i))
                        pv[i] = __hip_atomic_load(hsrc + wdv[i],
                                                  __ATOMIC_RELAXED, __HIP_MEMORY_SCOPE_AGENT);
                unsigned nm = 0;
#pragma unroll
                for (int i = 0; i < 8; ++i)
                    if (msk & (1u << i))
                        nm |= ((pv[i] & 0xFFFFull) == 0xFFFFull) ? (1u << i) : 0u;
                msk = nm;
            }
        }

        // ---- stage into LDS ----
#pragma unroll
        for (int i = 0; i < 8; ++i) {
            int bl = wdv[i] >> 7, r = wdv[i] & 127;
            int c = r >> 1, half = r & 1;
            *reinterpret_cast<ull*>(&hl[bl * 512 + ((c ^ (bl & 7)) << 3) + (half << 2)]) = pv[i];
        }
        __syncthreads();                 // barA: hl complete

        // ---- acc init from G4 (reg g = gate) ----
        f32x4 acc[2][2];
#pragma unroll
        for (int mt = 0; mt < 2; ++mt)
#pragma unroll
            for (int nt = 0; nt < 2; ++nt) {
                const unsigned short* gs = reinterpret_cast<const unsigned short*>(&gv[mt][nt]);
                f32x4 av;
#pragma unroll
                for (int g = 0; g < 4; ++g) av[g] = us2f(gs[g]);
                acc[mt][nt] = av;
            }

        // ---- MFMA: 16 kt x (2 LDS B-frags + 4 mfma), weights in regs ----
#pragma unroll
        for (int kt = 0; kt < 16; ++kt) {
            bf8v bfv[2];
#pragma unroll
            for (int nt = 0; nt < 2; ++nt) {
                int bl = nt * 16 + lo16;
                int c  = kt * 4 + hi4;
                bfv[nt] = *reinterpret_cast<const bf8v*>(
                    &hl[bl * 512 + ((c ^ (bl & 7)) << 3)]);
            }
#pragma unroll
            for (int mt = 0; mt < 2; ++mt)
#pragma unroll
                for (int nt = 0; nt < 2; ++nt)
                    acc[mt][nt] = __builtin_amdgcn_mfma_f32_16x16x32_bf16(
                        afr[mt][kt], bfv[nt], acc[mt][nt], 0, 0, 0);
        }

        // ---- pointwise: lane owns (u,b), 4 gates in regs; write h to bounce ----
#pragma unroll
        for (int mt = 0; mt < 2; ++mt)
#pragma unroll
            for (int nt = 0; nt < 2; ++nt) {
                bool msk = (t < len_[nt]);
                float i_ = sigm(acc[mt][nt][0]);
                float j_ = tanhf(acc[mt][nt][1]);
                float f_ = sigm(acc[mt][nt][2] + 1.0f);   // FORGET_BIAS
                float o_ = sigm(acc[mt][nt][3]);
                float cn = f_ * c_st[mt][nt] + i_ * j_;
                float hn = o_ * tanhf(cn);
                if (msk) c_st[mt][nt] = cn;
                h_st[mt][nt] = msk ? hn : h_st[mt][nt];
                hout[(nt * 16 + lo16) * 64 + w * 8 + mt * 4 + hi4] = f2us(h_st[mt][nt]);
            }
        __syncthreads();                 // barB: hout complete

        // ---- fire-and-forget h_{t+1} stores: 512 x 8B atomics ----
        {
            int bl = tid >> 4, uq = (tid & 15) * 4;
            ull v = *reinterpret_cast<const ull*>(&hout[bl * 64 + uq]);
            unsigned short* hdst = hseq + ((size_t)((t + 1) * 2 + d) * 64
                                           + bh * 32 + bl) * 512 + cg * 64 + uq;
            __hip_atomic_store(reinterpret_cast<ull*>(hdst), v,
                               __ATOMIC_RELAXED, __HIP_MEMORY_SCOPE_AGENT);
        }

        // ---- hcat stores ----
#pragma unroll
        for (int mt = 0; mt < 2; ++mt)
#pragma unroll
            for (int nt = 0; nt < 2; ++nt) {
                int b = bh * 32 + nt * 16 + lo16;
                int u = u0 + mt * 4 + hi4;
                bool msk = (t < len_[nt]);
                int p = (d == 1 && msk) ? (len_[nt] - 1 - t) : t;
                hcat[((size_t)p * 64 + b) * TWOH + (size_t)d * 512 + u] =
                    __float2bfloat16(msk ? h_st[mt][nt] : 0.f);
            }
    }
}

// ---------------- dense + softmax: out[b][s][c] ----------------
__global__ __launch_bounds__(256)
void dense_softmax(const bf16* __restrict__ h, const float* __restrict__ wd,
                   const float* __restrict__ bd, float* __restrict__ out)
{
    __shared__ __align__(16) bf16 wdT[NCLS][1032];
    for (int i = threadIdx.x; i < TWOH * NCLS; i += 256) {
        int k = i / NCLS, c = i % NCLS;    // wd[k][c]
        wdT[c][k] = __float2bfloat16(wd[i]);
    }
    __syncthreads();
    const int c  = threadIdx.x & 31;
    const int rl = threadIdx.x >> 5;
#pragma unroll 1
    for (int pass = 0; pass < 8; ++pass) {
        int r = blockIdx.x * 64 + pass * 8 + rl;   // r = s*BATCH + b
        const bf16* hrow = h + (size_t)r * TWOH;
        float acc = -1e30f;
        if (c < NCLS) {
            acc = 0.f;
            for (int k = 0; k < TWOH; k += 8) {
                uint4 hv = *reinterpret_cast<const uint4*>(hrow + k);
                uint4 wv = *reinterpret_cast<const uint4*>(&wdT[c][k]);
                const unsigned short* hs  = reinterpret_cast<const unsigned short*>(&hv);
                const unsigned short* wsp = reinterpret_cast<const unsigned short*>(&wv);
#pragma unroll
                for (int j = 0; j < 8; ++j) acc += us2f(hs[j]) * us2f(wsp[j]);
            }
            acc += bd[c];
        }
        float mx = acc;
#pragma unroll
        for (int o = 16; o; o >>= 1) mx = fmaxf(mx, __shfl_xor(mx, o, 32));
        float e = (c < NCLS) ? __expf(acc - mx) : 0.f;
        float sm = e;
#pragma unroll
        for (int o = 16; o; o >>= 1) sm += __shfl_xor(sm, o, 32);
        if (c < NCLS) {
            int s = r >> 6, b = r & 63;
            out[((size_t)b * S_LEN + s) * NCLS + c] = e / sm;
        }
    }
}

extern "C" void kernel_launch(void* const* d_in, const int* in_sizes, int n_in,
                              void* d_out, int out_size, void* d_ws, size_t ws_size,
                              hipStream_t stream)
{
    const int*   ids   = (const int*)  d_in[0];
    const int*   lens  = (const int*)  d_in[1];
    const float* emb   = (const float*)d_in[2];
    const float* w_fw0 = (const float*)d_in[3];
    const float* b_fw0 = (const float*)d_in[4];
    const float* w_bw0 = (const float*)d_in[5];
    const float* b_bw0 = (const float*)d_in[6];
    const float* w_fw1 = (const float*)d_in[7];
    const float* b_fw1 = (const float*)d_in[8];
    const float* w_bw1 = (const float*)d_in[9];
    const float* b_bw1 = (const float*)d_in[10];
    const float* wd    = (const float*)d_in[11];
    const float* bd    = (const float*)d_in[12];
    float* out = (float*)d_out;

    char* ws = (char*)d_ws;
    size_t off = 0;
    auto alloc = [&](size_t bytes) {
        void* p = ws + off;
        off += (bytes + 255) & ~(size_t)255;
        return p;
    };
    // ws budget 256 MiB (R15 post-mortem). Total = 253.9 MB.
    const size_t hseq_bytes = (size_t)(S_LEN + 1) * 2 * BATCH * HID * 2;  // 33.69 MB
    bf16*  x      = (bf16*) alloc((size_t)S_LEN * BATCH * EPAD * 2);      // 10.49 MB
    bf16*  G4     = (bf16*) alloc((size_t)2 * S_LEN * BATCH * G4H * 2);   // 134.2 MB
    bf16*  hcat0  = (bf16*) alloc((size_t)S_LEN * BATCH * TWOH * 2);      // 33.55 MB
    bf16*  hcat1  = (bf16*) alloc((size_t)S_LEN * BATCH * TWOH * 2);      // 33.55 MB
    bf16*  whTb   = (bf16*) alloc((size_t)4 * 512 * 4 * 512 * 2);         //  8.39 MB
    // scratch union: per-layer wxTb (8.39 MB) DURING gates, then hseq (33.69 MB)
    // DURING lstm — never live simultaneously (stream-ordered).
    void*  scratch = alloc(hseq_bytes);                                    // 33.69 MB

    embed_kernel<<<S_LEN * BATCH, 128, 0, stream>>>(ids, emb, x);
    wtrans_kernel<<<dim3(16, 64, 4), dim3(32, 32), 0, stream>>>(w_fw0, w_bw0, w_fw1, w_bw1, whTb);

    for (int layer = 0; layer < 2; ++layer) {
        const bf16* Ain   = layer ? hcat0 : x;
        int strideA       = layer ? TWOH : EPAD;
        int K             = layer ? 1024 : EPAD;
        const float* Wf   = layer ? w_fw1 : w_fw0;
        const float* Wb   = layer ? w_bw1 : w_bw0;
        int D             = layer ? TWOH : EMB;
        const float* bfp  = layer ? b_fw1 : b_fw0;
        const float* bbp  = layer ? b_bw1 : b_bw0;
        bf16* hcat        = layer ? hcat1 : hcat0;

        // phase 1: scratch = wxTb for this layer
        wxtrans_kernel<<<dim3(32, 64, 2), dim3(32, 32), 0, stream>>>(Wf, Wb, D, (bf16*)scratch);
        gates_mfma<<<dim3(64, 16, 2), 512, 0, stream>>>(
            Ain, strideA, K, (const bf16*)scratch, bfp, bbp, lens, G4);

        // phase 2: scratch = hseq (sentinel-init all slots, zero slot 0)
        hipMemsetAsync(scratch, 0xFF, hseq_bytes, stream);
        hipMemsetAsync(scratch, 0x00, (size_t)2 * BATCH * HID * 2, stream);

        const bf16*  Gp   = G4;
        const bf16*  whp  = whTb + (size_t)layer * 2 * 512 * 4 * 512;
        const int*   lnp  = lens;
        unsigned short* hsp = (unsigned short*)scratch;
        bf16*        hcp  = hcat;
        void* args[5] = { &Gp, &whp, &lnp, &hsp, &hcp };
        hipLaunchCooperativeKernel(lstm_seq, dim3(32), dim3(512), args, 0, stream);
    }
    dense_softmax<<<256, 256, 0, stream>>>(hcat1, wd, bd, out);

    (void)in_sizes; (void)n_in; (void)out_size; (void)ws_size;
}